// Round 15
// baseline (207.423 us; speedup 1.0000x reference)
//
#include <hip/hip_runtime.h>
#include <hip/hip_bf16.h>
#include <math.h>

// AGTBlock. Restructures:
//  - Wp2 pulled out of the edge sum (linear): node GEMM fused into final.
//  - MLP+QKV fused, 32-row blocks x 512 thr (2 row-groups x 4 col-slices):
//    B-weight L2 traffic halved vs 16-row blocks; x read f32 (cvt inline);
//    h1,h in LDS; QKV stored fp8.
//  - attn (r10-proven): 16-edge chunks, fp8 MFMA QK dots, scalar posMLP,
//    single-pass exp (alphas tiny -> no max shift).
//  - final at 16-row blocks (625): MFMA Wp2 GEMM + 2x LayerNorm.
// launches: memset, prep(transpose+hist), scan, scatter, mlpqkv, attn, final.

#define NN 10000
#define NE 320000

typedef __bf16 bf16;
typedef __bf16 bf16x8 __attribute__((ext_vector_type(8)));
typedef __bf16 bf16x4 __attribute__((ext_vector_type(4)));
typedef float f32x4 __attribute__((ext_vector_type(4)));
typedef unsigned char u8;

__device__ __forceinline__ float wave_sum(float v) {
#pragma unroll
  for (int off = 32; off; off >>= 1) v += __shfl_xor(v, off, 64);
  return v;
}

// is64 inline detect: high words of first 4 int64 edges are 0 (values < 2^31).
__device__ __forceinline__ int detect64(const int* __restrict__ ei) {
  return (ei[1] | ei[3] | ei[5] | ei[7]) == 0;
}

__device__ __forceinline__ void load_edge(const int* __restrict__ ei, int is64,
                                          int e, int& s, int& dn) {
  if (is64) {
    const long long* e64 = (const long long*)ei;
    s = (int)e64[e];
    dn = (int)e64[NE + e];
  } else {
    s = ei[e];
    dn = ei[NE + e];
  }
  s = min(max(s, 0), NN - 1);
  dn = min(max(dn, 0), NN - 1);
}

// ------- prep: transpose 6 weights (->bf16) + edge histogram -------
struct PrepArgs { const float* w[6]; bf16* o[6]; const int* ei; int* deg; };

__global__ __launch_bounds__(256) void prep_kernel(PrepArgs pa) {
  int b = blockIdx.x;
  if (b < 384) {  // 6 mats x 64 tiles of 32x32: o[n][k] = w[k][n]
    int t = b & 63, mat = b >> 6;
    int tr = (t >> 3) * 32, tc = (t & 7) * 32;
    __shared__ float tile[32][33];
    int tx = threadIdx.x & 31, ty = threadIdx.x >> 5;
    const float* w = pa.w[mat];
#pragma unroll
    for (int i = 0; i < 32; i += 8)
      tile[ty + i][tx] = w[(tr + ty + i) * 256 + tc + tx];
    __syncthreads();
    bf16* o = pa.o[mat];
#pragma unroll
    for (int i = 0; i < 32; i += 8)
      o[(tc + ty + i) * 256 + tr + tx] = (bf16)tile[tx][ty + i];
  } else {  // histogram of dst (deg pre-zeroed via memset)
    int is64 = detect64(pa.ei);
    int e = (b - 384) * 256 + threadIdx.x;
    if (e < NE) {
      int s, dn;
      load_edge(pa.ei, is64, e, s, dn);
      atomicAdd(&pa.deg[dn], 1);
    }
  }
}

__global__ __launch_bounds__(1024) void scan_kernel(
    const int* __restrict__ deg, int* __restrict__ rowptr,
    int* __restrict__ cursor) {
  __shared__ int wsum[16];
  int t = threadIdx.x, wid = t >> 6, lane = t & 63;
  int base = t * 10;
  int v[10];
  int s = 0;
#pragma unroll
  for (int i = 0; i < 10; ++i) {
    int idx = base + i;
    v[i] = (idx < NN) ? deg[idx] : 0;
    s += v[i];
  }
  int x = s;
#pragma unroll
  for (int off = 1; off < 64; off <<= 1) {
    int y = __shfl_up(x, off, 64);
    if (lane >= off) x += y;
  }
  if (lane == 63) wsum[wid] = x;
  __syncthreads();
  if (wid == 0) {
    int ws = (lane < 16) ? wsum[lane] : 0;
#pragma unroll
    for (int off = 1; off < 16; off <<= 1) {
      int y = __shfl_up(ws, off, 64);
      if (lane >= off) ws += y;
    }
    if (lane < 16) wsum[lane] = ws;
  }
  __syncthreads();
  int run = ((wid > 0) ? wsum[wid - 1] : 0) + x - s;  // exclusive prefix
#pragma unroll
  for (int i = 0; i < 10; ++i) {
    int idx = base + i;
    if (idx < NN) {
      cursor[idx] = run;
      run += v[i];
      rowptr[idx + 1] = run;
    }
  }
  if (t == 0) rowptr[0] = 0;
}

__global__ void scatter_kernel(const int* __restrict__ ei,
                               int* __restrict__ cursor, int* __restrict__ srcs) {
  int is64 = detect64(ei);
  int e = blockIdx.x * 256 + threadIdx.x;
  if (e < NE) {
    int s, dn;
    load_edge(ei, is64, e, s, dn);
    int slot = atomicAdd(&cursor[dn], 1);
    if (slot >= 0 && slot < NE) srcs[slot] = s;
  }
}

// ---- fused MLP+QKV: 313 blocks x 512 thr = 2 row-groups x 4 col-slices ----
// Each wave: 16 rows x 64 cols (4 frags, ILP-4). 32 rows/block halves B-weight
// L2 traffic; twin row-group waves re-read B through L1.
#define LP 264

__global__ __launch_bounds__(512) void mlpqkv_kernel(
    const float* __restrict__ x, const bf16* __restrict__ bt,
    const float* __restrict__ bm1, const float* __restrict__ bm2,
    const float* __restrict__ bq, const float* __restrict__ bk,
    const float* __restrict__ bv, bf16* __restrict__ hb,
    u8* __restrict__ Qf, u8* __restrict__ Kf, u8* __restrict__ Vf) {
  __shared__ bf16 lds[32 * LP];
  int w = threadIdx.x >> 6;
  int rg = w >> 2;                 // row-group 0/1
  int cb = (w & 3) * 64;           // col slice base
  int lane = threadIdx.x & 63;
  int lr = lane & 15, kh = lane >> 4;
  int rb = blockIdx.x * 32;
  int arow = min(rb + rg * 16 + lr, NN - 1);
  f32x4 acc[4];
  // stage 1: h1 slice -> LDS; A = x rows (f32 -> bf16 inline)
#pragma unroll
  for (int nf = 0; nf < 4; ++nf) acc[nf] = (f32x4){0, 0, 0, 0};
  {
    const float* Ap = x + (size_t)arow * 256 + kh * 8;
    const bf16* Bp = bt + (size_t)(cb + lr) * 256 + kh * 8;
#pragma unroll
    for (int kk = 0; kk < 8; ++kk) {
      float4 a0 = *(const float4*)(Ap + kk * 32);
      float4 a1 = *(const float4*)(Ap + kk * 32 + 4);
      bf16x8 af;
      af[0] = (bf16)a0.x; af[1] = (bf16)a0.y; af[2] = (bf16)a0.z; af[3] = (bf16)a0.w;
      af[4] = (bf16)a1.x; af[5] = (bf16)a1.y; af[6] = (bf16)a1.z; af[7] = (bf16)a1.w;
#pragma unroll
      for (int nf = 0; nf < 4; ++nf) {
        bf16x8 bfr = *(const bf16x8*)(Bp + nf * 16 * 256 + kk * 32);
        acc[nf] = __builtin_amdgcn_mfma_f32_16x16x32_bf16(af, bfr, acc[nf], 0, 0, 0);
      }
    }
  }
#pragma unroll
  for (int nf = 0; nf < 4; ++nf) {
    int c = cb + nf * 16 + lr;
    float b1 = bm1[c];
#pragma unroll
    for (int j = 0; j < 4; ++j)
      lds[(rg * 16 + kh * 4 + j) * LP + c] = (bf16)fmaxf(acc[nf][j] + b1, 0.0f);
  }
  __syncthreads();
  // stage 2: h = h1(LDS) @ Wm2 + bm2 -> LDS + hb
  bf16x8 haf[8];
#pragma unroll
  for (int kk = 0; kk < 8; ++kk)
    haf[kk] = *(const bf16x8*)(lds + (rg * 16 + lr) * LP + kh * 8 + kk * 32);
#pragma unroll
  for (int nf = 0; nf < 4; ++nf) acc[nf] = (f32x4){0, 0, 0, 0};
  {
    const bf16* Bp = bt + 65536 + (size_t)(cb + lr) * 256 + kh * 8;
#pragma unroll
    for (int kk = 0; kk < 8; ++kk) {
#pragma unroll
      for (int nf = 0; nf < 4; ++nf) {
        bf16x8 bfr = *(const bf16x8*)(Bp + nf * 16 * 256 + kk * 32);
        acc[nf] = __builtin_amdgcn_mfma_f32_16x16x32_bf16(haf[kk], bfr, acc[nf], 0, 0, 0);
      }
    }
  }
  __syncthreads();  // all h1 fragment reads complete before overwrite
#pragma unroll
  for (int nf = 0; nf < 4; ++nf) {
    int c = cb + nf * 16 + lr;
    float b2 = bm2[c];
#pragma unroll
    for (int j = 0; j < 4; ++j) {
      int r = rb + rg * 16 + kh * 4 + j;
      float v = acc[nf][j] + b2;
      lds[(rg * 16 + kh * 4 + j) * LP + c] = (bf16)v;
      if (r < NN) hb[(size_t)r * 256 + c] = (bf16)v;
    }
  }
  __syncthreads();
  // stage 3: Q,K,V = h(LDS) @ W* + b* -> fp8
#pragma unroll
  for (int kk = 0; kk < 8; ++kk)
    haf[kk] = *(const bf16x8*)(lds + (rg * 16 + lr) * LP + kh * 8 + kk * 32);
  const float* bias3[3] = {bq, bk, bv};
  u8* out3[3] = {Qf, Kf, Vf};
#pragma unroll
  for (int seg = 0; seg < 3; ++seg) {
#pragma unroll
    for (int nf = 0; nf < 4; ++nf) acc[nf] = (f32x4){0, 0, 0, 0};
    const bf16* Bp = bt + (size_t)(2 + seg) * 65536 + (size_t)(cb + lr) * 256 + kh * 8;
#pragma unroll
    for (int kk = 0; kk < 8; ++kk) {
#pragma unroll
      for (int nf = 0; nf < 4; ++nf) {
        bf16x8 bfr = *(const bf16x8*)(Bp + nf * 16 * 256 + kk * 32);
        acc[nf] = __builtin_amdgcn_mfma_f32_16x16x32_bf16(haf[kk], bfr, acc[nf], 0, 0, 0);
      }
    }
    u8* o = out3[seg];
    const float* bb = bias3[seg];
#pragma unroll
    for (int nf = 0; nf < 4; ++nf) {
      int c = cb + nf * 16 + lr;
      float bx = bb[c];
#pragma unroll
      for (int j = 0; j < 4; ++j) {
        int r = rb + rg * 16 + kh * 4 + j;
        if (r < NN) {
          float v = acc[nf][j] + bx;
          int pk = __builtin_amdgcn_cvt_pk_fp8_f32(v, v, 0, false);
          o[(size_t)r * 256 + c] = (u8)(pk & 0xff);
        }
      }
    }
  }
}

// ------- per-dst attention (r10-proven): fp8 MFMA QK, scalar posMLP -------
__global__ __launch_bounds__(256) void attn_kernel(
    const u8* __restrict__ Qf, const u8* __restrict__ Kf, const u8* __restrict__ Vf,
    const float* __restrict__ pos, const float* __restrict__ Wp1, const float* __restrict__ bp1,
    const int* __restrict__ rowptr, const int* __restrict__ srcs,
    bf16* __restrict__ acc1, bf16* __restrict__ acc2, float* __restrict__ sattn) {
  int n = blockIdx.x * 4 + (threadIdx.x >> 6);
  int lane = threadIdx.x & 63;
  int lr = lane & 15, kh = lane >> 4;
  int d = lane * 4;
  int e0 = min(max(rowptr[n], 0), NE);
  int e1 = min(max(rowptr[n + 1], e0), NE);
  long long qfr[8];
#pragma unroll
  for (int m = 0; m < 8; ++m)
    qfr[m] = *(const long long*)(Qf + (size_t)n * 256 + m * 32 + kh * 8);
  float px = pos[n * 3], py = pos[n * 3 + 1], pz = pos[n * 3 + 2];
  float w0[4], w1[4], w2[4], bp[4];
#pragma unroll
  for (int j = 0; j < 4; ++j) {
    w0[j] = Wp1[d + j];
    w1[j] = Wp1[256 + d + j];
    w2[j] = Wp1[512 + d + j];
    bp[j] = bp1[d + j];
  }
  float aV[4] = {0, 0, 0, 0}, aP[4] = {0, 0, 0, 0};
  float dpart = 0.0f;
  for (int base = e0; base < e1; base += 16) {
    int sv = srcs[min(base + lr, e1 - 1)];
    f32x4 al = {0.0f, 0.0f, 0.0f, 0.0f};
#pragma unroll
    for (int m = 0; m < 8; ++m) {
      long long kfr = *(const long long*)(Kf + (size_t)sv * 256 + m * 32 + kh * 8);
      al = __builtin_amdgcn_mfma_f32_16x16x32_fp8_fp8(kfr, qfr[m], al, 0, 0, 0);
    }
    float wg[4];
#pragma unroll
    for (int j = 0; j < 4; ++j) {
      int e = base + kh * 4 + j;
      wg[j] = (e < e1) ? __expf(al[j] * 0.0625f) : 0.0f;  // alpha/sqrt(256)
      dpart += wg[j];
    }
#pragma unroll
    for (int ii = 0; ii < 4; ++ii) {
      if (base + ii * 4 < e1) {
#pragma unroll
        for (int j = 0; j < 4; ++j) {
          float we = __int_as_float(
              __builtin_amdgcn_readlane(__float_as_int(wg[j]), ii * 16));
          int se = __builtin_amdgcn_readlane(sv, ii * 4 + j);
          unsigned vw = *(const unsigned*)(Vf + (size_t)se * 256 + lane * 4);
          float vvf[4];
          vvf[0] = __builtin_amdgcn_cvt_f32_fp8(vw, 0);
          vvf[1] = __builtin_amdgcn_cvt_f32_fp8(vw, 1);
          vvf[2] = __builtin_amdgcn_cvt_f32_fp8(vw, 2);
          vvf[3] = __builtin_amdgcn_cvt_f32_fp8(vw, 3);
          float rx = pos[se * 3] - px, ry = pos[se * 3 + 1] - py,
                rz = pos[se * 3 + 2] - pz;
#pragma unroll
          for (int jj = 0; jj < 4; ++jj) {
            float p1 = fmaf(rx, w0[jj], fmaf(ry, w1[jj], fmaf(rz, w2[jj], bp[jj])));
            p1 = fmaxf(p1, 0.0f);
            aV[jj] = fmaf(we, vvf[jj], aV[jj]);
            aP[jj] = fmaf(we, p1, aP[jj]);
          }
        }
      }
    }
  }
  float denom = wave_sum(dpart) * (1.0f / 16.0f);  // each edge replicated x16
  float r = 1.0f / (denom + 1e-16f);
  if (lane == 0) sattn[n] = denom * r;
  bf16x4 o1, o2;
#pragma unroll
  for (int j = 0; j < 4; ++j) {
    o1[j] = (bf16)(aV[j] * r);
    o2[j] = (bf16)(aP[j] * r);
  }
  *(bf16x4*)(acc1 + (size_t)n * 256 + d) = o1;
  *(bf16x4*)(acc2 + (size_t)n * 256 + d) = o2;
}

// ------- final: tmp = acc2@Wp2 (MFMA) + residuals + 2x LayerNorm -------
__global__ __launch_bounds__(256) void final_kernel(
    const bf16* __restrict__ acc2, const bf16* __restrict__ Bt5,
    const bf16* __restrict__ acc1, const float* __restrict__ sattn,
    const float* __restrict__ bp2, const bf16* __restrict__ hb,
    const float* __restrict__ x, const float* __restrict__ g1,
    const float* __restrict__ b1n, const float* __restrict__ g2,
    const float* __restrict__ b2n, float* __restrict__ out) {
  __shared__ float red[2][4][16];
  int w = threadIdx.x >> 6, lane = threadIdx.x & 63;
  int lr = lane & 15, kh = lane >> 4;
  int rb = blockIdx.x * 16;  // NN = 625*16 exactly
  int arow = rb + lr;
  const bf16* Ap = acc2 + (size_t)arow * 256 + kh * 8;
  const bf16* Bp = Bt5 + (size_t)(w * 64 + lr) * 256 + kh * 8;
  f32x4 acc[4];
#pragma unroll
  for (int nf = 0; nf < 4; ++nf) acc[nf] = (f32x4){0, 0, 0, 0};
#pragma unroll
  for (int kk = 0; kk < 8; ++kk) {
    bf16x8 af = *(const bf16x8*)(Ap + kk * 32);
#pragma unroll
    for (int nf = 0; nf < 4; ++nf) {
      bf16x8 bfr = *(const bf16x8*)(Bp + nf * 16 * 256 + kk * 32);
      acc[nf] = __builtin_amdgcn_mfma_f32_16x16x32_bf16(af, bfr, acc[nf], 0, 0, 0);
    }
  }
  int rows[4];
  float sr[4];
#pragma unroll
  for (int j = 0; j < 4; ++j) {
    rows[j] = rb + kh * 4 + j;
    sr[j] = sattn[rows[j]];
  }
  // phase A: v = tmp + acc1 + s*bp2 + h ; mean/var via sum & sumsq
  float s1[4] = {0, 0, 0, 0}, s2[4] = {0, 0, 0, 0};
#pragma unroll
  for (int nf = 0; nf < 4; ++nf) {
    int c = w * 64 + nf * 16 + lr;
#pragma unroll
    for (int j = 0; j < 4; ++j) {
      size_t idx = (size_t)rows[j] * 256 + c;
      float v = acc[nf][j] + (float)acc1[idx] + sr[j] * bp2[c] + (float)hb[idx];
      acc[nf][j] = v;
      s1[j] += v;
      s2[j] += v * v;
    }
  }
#pragma unroll
  for (int j = 0; j < 4; ++j) {
#pragma unroll
    for (int off = 1; off < 16; off <<= 1) {
      s1[j] += __shfl_xor(s1[j], off, 64);
      s2[j] += __shfl_xor(s2[j], off, 64);
    }
  }
  if (lr == 0) {
#pragma unroll
    for (int j = 0; j < 4; ++j) {
      red[0][w][kh * 4 + j] = s1[j];
      red[1][w][kh * 4 + j] = s2[j];
    }
  }
  __syncthreads();
  float mu[4], rstd[4];
#pragma unroll
  for (int j = 0; j < 4; ++j) {
    int r = kh * 4 + j;
    float t1 = red[0][0][r] + red[0][1][r] + red[0][2][r] + red[0][3][r];
    float t2 = red[1][0][r] + red[1][1][r] + red[1][2][r] + red[1][3][r];
    mu[j] = t1 * (1.0f / 256.0f);
    rstd[j] = rsqrtf(t2 * (1.0f / 256.0f) - mu[j] * mu[j] + 1e-5f);
  }
  __syncthreads();
  // phase B: u = LN1*g1 + b1n + x ; second mean/var
#pragma unroll
  for (int j = 0; j < 4; ++j) { s1[j] = 0; s2[j] = 0; }
#pragma unroll
  for (int nf = 0; nf < 4; ++nf) {
    int c = w * 64 + nf * 16 + lr;
#pragma unroll
    for (int j = 0; j < 4; ++j) {
      float u = (acc[nf][j] - mu[j]) * rstd[j] * g1[c] + b1n[c] +
                x[(size_t)rows[j] * 256 + c];
      acc[nf][j] = u;
      s1[j] += u;
      s2[j] += u * u;
    }
  }
#pragma unroll
  for (int j = 0; j < 4; ++j) {
#pragma unroll
    for (int off = 1; off < 16; off <<= 1) {
      s1[j] += __shfl_xor(s1[j], off, 64);
      s2[j] += __shfl_xor(s2[j], off, 64);
    }
  }
  if (lr == 0) {
#pragma unroll
    for (int j = 0; j < 4; ++j) {
      red[0][w][kh * 4 + j] = s1[j];
      red[1][w][kh * 4 + j] = s2[j];
    }
  }
  __syncthreads();
#pragma unroll
  for (int j = 0; j < 4; ++j) {
    int r = kh * 4 + j;
    float t1 = red[0][0][r] + red[0][1][r] + red[0][2][r] + red[0][3][r];
    float t2 = red[1][0][r] + red[1][1][r] + red[1][2][r] + red[1][3][r];
    mu[j] = t1 * (1.0f / 256.0f);
    rstd[j] = rsqrtf(t2 * (1.0f / 256.0f) - mu[j] * mu[j] + 1e-5f);
  }
  // phase C: out = LN2*g2 + b2n
#pragma unroll
  for (int j = 0; j < 4; ++j) {
#pragma unroll
    for (int nf = 0; nf < 4; ++nf) {
      int c = w * 64 + nf * 16 + lr;
      out[(size_t)rows[j] * 256 + c] =
          (acc[nf][j] - mu[j]) * rstd[j] * g2[c] + b2n[c];
    }
  }
}

extern "C" void kernel_launch(void* const* d_in, const int* in_sizes, int n_in,
                              void* d_out, int out_size, void* d_ws, size_t ws_size,
                              hipStream_t stream) {
  (void)in_sizes; (void)n_in; (void)out_size; (void)ws_size;
  const float* x   = (const float*)d_in[0];
  const int*   ei  = (const int*)d_in[1];
  const float* pos = (const float*)d_in[2];
  const float* Wm1 = (const float*)d_in[3];
  const float* bm1 = (const float*)d_in[4];
  const float* Wm2 = (const float*)d_in[5];
  const float* bm2 = (const float*)d_in[6];
  const float* Wq  = (const float*)d_in[7];
  const float* bq  = (const float*)d_in[8];
  const float* Wk  = (const float*)d_in[9];
  const float* bk  = (const float*)d_in[10];
  const float* Wv  = (const float*)d_in[11];
  const float* bv  = (const float*)d_in[12];
  const float* Wp1 = (const float*)d_in[13];
  const float* bp1 = (const float*)d_in[14];
  const float* Wp2 = (const float*)d_in[15];
  const float* bp2 = (const float*)d_in[16];
  const float* g1  = (const float*)d_in[17];
  const float* b1n = (const float*)d_in[18];
  const float* g2  = (const float*)d_in[19];
  const float* b2n = (const float*)d_in[20];

  const size_t ND = (size_t)NN * 256;
  char* p = (char*)d_ws;
  auto alloc = [&](size_t bytes) {
    char* r = p;
    p += (bytes + 255) & ~(size_t)255;
    return r;
  };
  bf16* btbase = (bf16*)alloc(6 * 65536 * sizeof(bf16));
  bf16* hb    = (bf16*)alloc(ND * 2);
  u8*   Qf    = (u8*)alloc(ND);
  u8*   Kf    = (u8*)alloc(ND);
  u8*   Vf    = (u8*)alloc(ND);
  bf16* acc1  = (bf16*)alloc(ND * 2);
  bf16* acc2  = (bf16*)alloc(ND * 2);
  float* sattn = (float*)alloc(NN * 4);
  int* deg    = (int*)alloc(NN * 4);
  int* rowptr = (int*)alloc((NN + 1) * 4);
  int* cursor = (int*)alloc(NN * 4);
  int* srcs   = (int*)alloc(NE * 4);

  hipMemsetAsync(deg, 0, NN * 4, stream);

  PrepArgs pa;
  pa.w[0] = Wm1; pa.w[1] = Wm2; pa.w[2] = Wq; pa.w[3] = Wk; pa.w[4] = Wv; pa.w[5] = Wp2;
  for (int i = 0; i < 6; ++i) pa.o[i] = btbase + i * 65536;
  pa.ei = ei; pa.deg = deg;
  prep_kernel<<<384 + (NE + 255) / 256, 256, 0, stream>>>(pa);

  scan_kernel<<<1, 1024, 0, stream>>>(deg, rowptr, cursor);
  scatter_kernel<<<(NE + 255) / 256, 256, 0, stream>>>(ei, cursor, srcs);

  mlpqkv_kernel<<<(NN + 31) / 32, 512, 0, stream>>>(x, btbase, bm1, bm2, bq, bk,
                                                    bv, hb, Qf, Kf, Vf);

  attn_kernel<<<NN / 4, 256, 0, stream>>>(Qf, Kf, Vf, pos, Wp1, bp1, rowptr, srcs,
                                          acc1, acc2, sattn);

  final_kernel<<<NN / 16, 256, 0, stream>>>(acc2, btbase + 5 * 65536, acc1, sattn,
                                            bp2, hb, x, g1, b1n, g2, b2n,
                                            (float*)d_out);
}

// Round 16
// 189.690 us; speedup vs baseline: 1.0935x; 1.0935x over previous
//
#include <hip/hip_runtime.h>
#include <hip/hip_bf16.h>
#include <math.h>

// AGTBlock. r13 structure (best: 187us) + stage-3 QKV interleave in mlpqkv.
//  - Wp2 pulled out of the edge sum (linear): node GEMM fused into final.
//  - MLP+QKV fused at 16-row tiles (625 blocks x 4 waves, 4 frags/wave);
//    stage3 issues Q,K,V B-loads interleaved (3 indep MFMA chains) for 3x MLP.
//  - attn (r10-proven): 16-edge chunks, fp8 MFMA QK dots, scalar posMLP,
//    single-pass exp (alphas tiny -> no max shift).
//  - final at 16-row blocks (625): MFMA Wp2 GEMM + 2x LayerNorm.
// launches: memset, prep(transpose+cvt+hist), scan, scatter, mlpqkv, attn, final.

#define NN 10000
#define NE 320000

typedef __bf16 bf16;
typedef __bf16 bf16x8 __attribute__((ext_vector_type(8)));
typedef __bf16 bf16x4 __attribute__((ext_vector_type(4)));
typedef float f32x4 __attribute__((ext_vector_type(4)));
typedef unsigned char u8;

__device__ __forceinline__ float wave_sum(float v) {
#pragma unroll
  for (int off = 32; off; off >>= 1) v += __shfl_xor(v, off, 64);
  return v;
}

// is64 inline detect: high words of first 4 int64 edges are 0 (values < 2^31).
__device__ __forceinline__ int detect64(const int* __restrict__ ei) {
  return (ei[1] | ei[3] | ei[5] | ei[7]) == 0;
}

__device__ __forceinline__ void load_edge(const int* __restrict__ ei, int is64,
                                          int e, int& s, int& dn) {
  if (is64) {
    const long long* e64 = (const long long*)ei;
    s = (int)e64[e];
    dn = (int)e64[NE + e];
  } else {
    s = ei[e];
    dn = ei[NE + e];
  }
  s = min(max(s, 0), NN - 1);
  dn = min(max(dn, 0), NN - 1);
}

// ------- prep: transpose 6 weights (->bf16) + cvt x->bf16 + edge histogram -------
struct PrepArgs { const float* w[6]; bf16* o[6]; const float* x; bf16* xb;
                  const int* ei; int* deg; };

__global__ __launch_bounds__(256) void prep_kernel(PrepArgs pa) {
  int b = blockIdx.x;
  if (b < 384) {  // 6 mats x 64 tiles of 32x32: o[n][k] = w[k][n]
    int t = b & 63, mat = b >> 6;
    int tr = (t >> 3) * 32, tc = (t & 7) * 32;
    __shared__ float tile[32][33];
    int tx = threadIdx.x & 31, ty = threadIdx.x >> 5;
    const float* w = pa.w[mat];
#pragma unroll
    for (int i = 0; i < 32; i += 8)
      tile[ty + i][tx] = w[(tr + ty + i) * 256 + tc + tx];
    __syncthreads();
    bf16* o = pa.o[mat];
#pragma unroll
    for (int i = 0; i < 32; i += 8)
      o[(tc + ty + i) * 256 + tr + tx] = (bf16)tile[tx][ty + i];
  } else if (b < 384 + 2500) {  // cvt 2.56M f32 -> bf16
    int i = ((b - 384) * 256 + threadIdx.x) * 4;
    float4 v = *(const float4*)(pa.x + i);
    bf16x4 o;
    o[0] = (bf16)v.x; o[1] = (bf16)v.y; o[2] = (bf16)v.z; o[3] = (bf16)v.w;
    *(bf16x4*)(pa.xb + i) = o;
  } else {  // histogram of dst (deg pre-zeroed via memset)
    int is64 = detect64(pa.ei);
    int e = (b - 2884) * 256 + threadIdx.x;
    if (e < NE) {
      int s, dn;
      load_edge(pa.ei, is64, e, s, dn);
      atomicAdd(&pa.deg[dn], 1);
    }
  }
}

__global__ __launch_bounds__(1024) void scan_kernel(
    const int* __restrict__ deg, int* __restrict__ rowptr,
    int* __restrict__ cursor) {
  __shared__ int wsum[16];
  int t = threadIdx.x, wid = t >> 6, lane = t & 63;
  int base = t * 10;
  int v[10];
  int s = 0;
#pragma unroll
  for (int i = 0; i < 10; ++i) {
    int idx = base + i;
    v[i] = (idx < NN) ? deg[idx] : 0;
    s += v[i];
  }
  int x = s;
#pragma unroll
  for (int off = 1; off < 64; off <<= 1) {
    int y = __shfl_up(x, off, 64);
    if (lane >= off) x += y;
  }
  if (lane == 63) wsum[wid] = x;
  __syncthreads();
  if (wid == 0) {
    int ws = (lane < 16) ? wsum[lane] : 0;
#pragma unroll
    for (int off = 1; off < 16; off <<= 1) {
      int y = __shfl_up(ws, off, 64);
      if (lane >= off) ws += y;
    }
    if (lane < 16) wsum[lane] = ws;
  }
  __syncthreads();
  int run = ((wid > 0) ? wsum[wid - 1] : 0) + x - s;  // exclusive prefix
#pragma unroll
  for (int i = 0; i < 10; ++i) {
    int idx = base + i;
    if (idx < NN) {
      cursor[idx] = run;
      run += v[i];
      rowptr[idx + 1] = run;
    }
  }
  if (t == 0) rowptr[0] = 0;
}

__global__ void scatter_kernel(const int* __restrict__ ei,
                               int* __restrict__ cursor, int* __restrict__ srcs) {
  int is64 = detect64(ei);
  int e = blockIdx.x * 256 + threadIdx.x;
  if (e < NE) {
    int s, dn;
    load_edge(ei, is64, e, s, dn);
    int slot = atomicAdd(&cursor[dn], 1);
    if (slot >= 0 && slot < NE) srcs[slot] = s;
  }
}

// ---------------- fused MLP+QKV: 16-row tiles, 625 blocks ----------------
// stage1 h1 -> LDS; stage2 h -> LDS + hb; stage3 Q,K,V interleaved -> fp8.
#define LP 264

__global__ __launch_bounds__(256) void mlpqkv_kernel(
    const bf16* __restrict__ xb, const bf16* __restrict__ bt,
    const float* __restrict__ bm1, const float* __restrict__ bm2,
    const float* __restrict__ bq, const float* __restrict__ bk,
    const float* __restrict__ bv, bf16* __restrict__ hb,
    u8* __restrict__ Qf, u8* __restrict__ Kf, u8* __restrict__ Vf) {
  __shared__ bf16 lds[16 * LP];
  int w = threadIdx.x >> 6, lane = threadIdx.x & 63;
  int lr = lane & 15, kh = lane >> 4;
  int rb = blockIdx.x * 16;
  int arow = min(rb + lr, NN - 1);
  f32x4 acc[4];
  // stage 1: h1 slice [16 x 64cols(w)] -> LDS
#pragma unroll
  for (int nf = 0; nf < 4; ++nf) acc[nf] = (f32x4){0, 0, 0, 0};
  {
    const bf16* Ap = xb + (size_t)arow * 256 + kh * 8;
    const bf16* Bp = bt + (size_t)(w * 64 + lr) * 256 + kh * 8;
#pragma unroll
    for (int kk = 0; kk < 8; ++kk) {
      bf16x8 af = *(const bf16x8*)(Ap + kk * 32);
#pragma unroll
      for (int nf = 0; nf < 4; ++nf) {
        bf16x8 bfr = *(const bf16x8*)(Bp + nf * 16 * 256 + kk * 32);
        acc[nf] = __builtin_amdgcn_mfma_f32_16x16x32_bf16(af, bfr, acc[nf], 0, 0, 0);
      }
    }
  }
#pragma unroll
  for (int nf = 0; nf < 4; ++nf) {
    int c = w * 64 + nf * 16 + lr;
    float b1 = bm1[c];
#pragma unroll
    for (int j = 0; j < 4; ++j)
      lds[(kh * 4 + j) * LP + c] = (bf16)fmaxf(acc[nf][j] + b1, 0.0f);
  }
  __syncthreads();
  // stage 2: h = h1(LDS) @ Wm2 + bm2 -> LDS + hb
  bf16x8 haf[8];
#pragma unroll
  for (int kk = 0; kk < 8; ++kk)
    haf[kk] = *(const bf16x8*)(lds + lr * LP + kh * 8 + kk * 32);
#pragma unroll
  for (int nf = 0; nf < 4; ++nf) acc[nf] = (f32x4){0, 0, 0, 0};
  {
    const bf16* Bp = bt + 65536 + (size_t)(w * 64 + lr) * 256 + kh * 8;
#pragma unroll
    for (int kk = 0; kk < 8; ++kk) {
#pragma unroll
      for (int nf = 0; nf < 4; ++nf) {
        bf16x8 bfr = *(const bf16x8*)(Bp + nf * 16 * 256 + kk * 32);
        acc[nf] = __builtin_amdgcn_mfma_f32_16x16x32_bf16(haf[kk], bfr, acc[nf], 0, 0, 0);
      }
    }
  }
  __syncthreads();  // h1 reads complete before overwrite
#pragma unroll
  for (int nf = 0; nf < 4; ++nf) {
    int c = w * 64 + nf * 16 + lr;
    float b2 = bm2[c];
#pragma unroll
    for (int j = 0; j < 4; ++j) {
      int r = rb + kh * 4 + j;
      float v = acc[nf][j] + b2;
      lds[(kh * 4 + j) * LP + c] = (bf16)v;
      if (r < NN) hb[(size_t)r * 256 + c] = (bf16)v;
    }
  }
  __syncthreads();
  // stage 3: Q,K,V = h(LDS) @ W* + b* -> fp8; three segments INTERLEAVED
  // (12 independent B-loads + 3 independent MFMA chains per kk step).
#pragma unroll
  for (int kk = 0; kk < 8; ++kk)
    haf[kk] = *(const bf16x8*)(lds + lr * LP + kh * 8 + kk * 32);
  f32x4 acc3[3][4];
#pragma unroll
  for (int seg = 0; seg < 3; ++seg)
#pragma unroll
    for (int nf = 0; nf < 4; ++nf) acc3[seg][nf] = (f32x4){0, 0, 0, 0};
  {
    const bf16* Bp = bt + 2 * 65536 + (size_t)(w * 64 + lr) * 256 + kh * 8;
#pragma unroll
    for (int kk = 0; kk < 8; ++kk) {
#pragma unroll
      for (int seg = 0; seg < 3; ++seg) {
#pragma unroll
        for (int nf = 0; nf < 4; ++nf) {
          bf16x8 bfr = *(const bf16x8*)(Bp + seg * 65536 + nf * 16 * 256 + kk * 32);
          acc3[seg][nf] =
              __builtin_amdgcn_mfma_f32_16x16x32_bf16(haf[kk], bfr, acc3[seg][nf], 0, 0, 0);
        }
      }
    }
  }
  const float* bias3[3] = {bq, bk, bv};
  u8* out3[3] = {Qf, Kf, Vf};
#pragma unroll
  for (int seg = 0; seg < 3; ++seg) {
    u8* o = out3[seg];
    const float* bb = bias3[seg];
#pragma unroll
    for (int nf = 0; nf < 4; ++nf) {
      int c = w * 64 + nf * 16 + lr;
      float bx = bb[c];
#pragma unroll
      for (int j = 0; j < 4; ++j) {
        int r = rb + kh * 4 + j;
        if (r < NN) {
          float v = acc3[seg][nf][j] + bx;
          int pk = __builtin_amdgcn_cvt_pk_fp8_f32(v, v, 0, false);
          o[(size_t)r * 256 + c] = (u8)(pk & 0xff);
        }
      }
    }
  }
}

// ------- per-dst attention (r10-proven): fp8 MFMA QK, scalar posMLP -------
__global__ __launch_bounds__(256) void attn_kernel(
    const u8* __restrict__ Qf, const u8* __restrict__ Kf, const u8* __restrict__ Vf,
    const float* __restrict__ pos, const float* __restrict__ Wp1, const float* __restrict__ bp1,
    const int* __restrict__ rowptr, const int* __restrict__ srcs,
    bf16* __restrict__ acc1, bf16* __restrict__ acc2, float* __restrict__ sattn) {
  int n = blockIdx.x * 4 + (threadIdx.x >> 6);
  int lane = threadIdx.x & 63;
  int lr = lane & 15, kh = lane >> 4;
  int d = lane * 4;
  int e0 = min(max(rowptr[n], 0), NE);
  int e1 = min(max(rowptr[n + 1], e0), NE);
  long long qfr[8];
#pragma unroll
  for (int m = 0; m < 8; ++m)
    qfr[m] = *(const long long*)(Qf + (size_t)n * 256 + m * 32 + kh * 8);
  float px = pos[n * 3], py = pos[n * 3 + 1], pz = pos[n * 3 + 2];
  float w0[4], w1[4], w2[4], bp[4];
#pragma unroll
  for (int j = 0; j < 4; ++j) {
    w0[j] = Wp1[d + j];
    w1[j] = Wp1[256 + d + j];
    w2[j] = Wp1[512 + d + j];
    bp[j] = bp1[d + j];
  }
  float aV[4] = {0, 0, 0, 0}, aP[4] = {0, 0, 0, 0};
  float dpart = 0.0f;
  for (int base = e0; base < e1; base += 16) {
    int sv = srcs[min(base + lr, e1 - 1)];
    f32x4 al = {0.0f, 0.0f, 0.0f, 0.0f};
#pragma unroll
    for (int m = 0; m < 8; ++m) {
      long long kfr = *(const long long*)(Kf + (size_t)sv * 256 + m * 32 + kh * 8);
      al = __builtin_amdgcn_mfma_f32_16x16x32_fp8_fp8(kfr, qfr[m], al, 0, 0, 0);
    }
    float wg[4];
#pragma unroll
    for (int j = 0; j < 4; ++j) {
      int e = base + kh * 4 + j;
      wg[j] = (e < e1) ? __expf(al[j] * 0.0625f) : 0.0f;  // alpha/sqrt(256)
      dpart += wg[j];
    }
#pragma unroll
    for (int ii = 0; ii < 4; ++ii) {
      if (base + ii * 4 < e1) {
#pragma unroll
        for (int j = 0; j < 4; ++j) {
          float we = __int_as_float(
              __builtin_amdgcn_readlane(__float_as_int(wg[j]), ii * 16));
          int se = __builtin_amdgcn_readlane(sv, ii * 4 + j);
          unsigned vw = *(const unsigned*)(Vf + (size_t)se * 256 + lane * 4);
          float vvf[4];
          vvf[0] = __builtin_amdgcn_cvt_f32_fp8(vw, 0);
          vvf[1] = __builtin_amdgcn_cvt_f32_fp8(vw, 1);
          vvf[2] = __builtin_amdgcn_cvt_f32_fp8(vw, 2);
          vvf[3] = __builtin_amdgcn_cvt_f32_fp8(vw, 3);
          float rx = pos[se * 3] - px, ry = pos[se * 3 + 1] - py,
                rz = pos[se * 3 + 2] - pz;
#pragma unroll
          for (int jj = 0; jj < 4; ++jj) {
            float p1 = fmaf(rx, w0[jj], fmaf(ry, w1[jj], fmaf(rz, w2[jj], bp[jj])));
            p1 = fmaxf(p1, 0.0f);
            aV[jj] = fmaf(we, vvf[jj], aV[jj]);
            aP[jj] = fmaf(we, p1, aP[jj]);
          }
        }
      }
    }
  }
  float denom = wave_sum(dpart) * (1.0f / 16.0f);  // each edge replicated x16
  float r = 1.0f / (denom + 1e-16f);
  if (lane == 0) sattn[n] = denom * r;
  bf16x4 o1, o2;
#pragma unroll
  for (int j = 0; j < 4; ++j) {
    o1[j] = (bf16)(aV[j] * r);
    o2[j] = (bf16)(aP[j] * r);
  }
  *(bf16x4*)(acc1 + (size_t)n * 256 + d) = o1;
  *(bf16x4*)(acc2 + (size_t)n * 256 + d) = o2;
}

// ------- final: tmp = acc2@Wp2 (MFMA) + residuals + 2x LayerNorm -------
__global__ __launch_bounds__(256) void final_kernel(
    const bf16* __restrict__ acc2, const bf16* __restrict__ Bt5,
    const bf16* __restrict__ acc1, const float* __restrict__ sattn,
    const float* __restrict__ bp2, const bf16* __restrict__ hb,
    const float* __restrict__ x, const float* __restrict__ g1,
    const float* __restrict__ b1n, const float* __restrict__ g2,
    const float* __restrict__ b2n, float* __restrict__ out) {
  __shared__ float red[2][4][16];
  int w = threadIdx.x >> 6, lane = threadIdx.x & 63;
  int lr = lane & 15, kh = lane >> 4;
  int rb = blockIdx.x * 16;  // NN = 625*16 exactly
  int arow = rb + lr;
  const bf16* Ap = acc2 + (size_t)arow * 256 + kh * 8;
  const bf16* Bp = Bt5 + (size_t)(w * 64 + lr) * 256 + kh * 8;
  f32x4 acc[4];
#pragma unroll
  for (int nf = 0; nf < 4; ++nf) acc[nf] = (f32x4){0, 0, 0, 0};
#pragma unroll
  for (int kk = 0; kk < 8; ++kk) {
    bf16x8 af = *(const bf16x8*)(Ap + kk * 32);
#pragma unroll
    for (int nf = 0; nf < 4; ++nf) {
      bf16x8 bfr = *(const bf16x8*)(Bp + nf * 16 * 256 + kk * 32);
      acc[nf] = __builtin_amdgcn_mfma_f32_16x16x32_bf16(af, bfr, acc[nf], 0, 0, 0);
    }
  }
  int rows[4];
  float sr[4];
#pragma unroll
  for (int j = 0; j < 4; ++j) {
    rows[j] = rb + kh * 4 + j;
    sr[j] = sattn[rows[j]];
  }
  // phase A: v = tmp + acc1 + s*bp2 + h ; mean/var via sum & sumsq
  float s1[4] = {0, 0, 0, 0}, s2[4] = {0, 0, 0, 0};
#pragma unroll
  for (int nf = 0; nf < 4; ++nf) {
    int c = w * 64 + nf * 16 + lr;
#pragma unroll
    for (int j = 0; j < 4; ++j) {
      size_t idx = (size_t)rows[j] * 256 + c;
      float v = acc[nf][j] + (float)acc1[idx] + sr[j] * bp2[c] + (float)hb[idx];
      acc[nf][j] = v;
      s1[j] += v;
      s2[j] += v * v;
    }
  }
#pragma unroll
  for (int j = 0; j < 4; ++j) {
#pragma unroll
    for (int off = 1; off < 16; off <<= 1) {
      s1[j] += __shfl_xor(s1[j], off, 64);
      s2[j] += __shfl_xor(s2[j], off, 64);
    }
  }
  if (lr == 0) {
#pragma unroll
    for (int j = 0; j < 4; ++j) {
      red[0][w][kh * 4 + j] = s1[j];
      red[1][w][kh * 4 + j] = s2[j];
    }
  }
  __syncthreads();
  float mu[4], rstd[4];
#pragma unroll
  for (int j = 0; j < 4; ++j) {
    int r = kh * 4 + j;
    float t1 = red[0][0][r] + red[0][1][r] + red[0][2][r] + red[0][3][r];
    float t2 = red[1][0][r] + red[1][1][r] + red[1][2][r] + red[1][3][r];
    mu[j] = t1 * (1.0f / 256.0f);
    rstd[j] = rsqrtf(t2 * (1.0f / 256.0f) - mu[j] * mu[j] + 1e-5f);
  }
  __syncthreads();
  // phase B: u = LN1*g1 + b1n + x ; second mean/var
#pragma unroll
  for (int j = 0; j < 4; ++j) { s1[j] = 0; s2[j] = 0; }
#pragma unroll
  for (int nf = 0; nf < 4; ++nf) {
    int c = w * 64 + nf * 16 + lr;
#pragma unroll
    for (int j = 0; j < 4; ++j) {
      float u = (acc[nf][j] - mu[j]) * rstd[j] * g1[c] + b1n[c] +
                x[(size_t)rows[j] * 256 + c];
      acc[nf][j] = u;
      s1[j] += u;
      s2[j] += u * u;
    }
  }
#pragma unroll
  for (int j = 0; j < 4; ++j) {
#pragma unroll
    for (int off = 1; off < 16; off <<= 1) {
      s1[j] += __shfl_xor(s1[j], off, 64);
      s2[j] += __shfl_xor(s2[j], off, 64);
    }
  }
  if (lr == 0) {
#pragma unroll
    for (int j = 0; j < 4; ++j) {
      red[0][w][kh * 4 + j] = s1[j];
      red[1][w][kh * 4 + j] = s2[j];
    }
  }
  __syncthreads();
#pragma unroll
  for (int j = 0; j < 4; ++j) {
    int r = kh * 4 + j;
    float t1 = red[0][0][r] + red[0][1][r] + red[0][2][r] + red[0][3][r];
    float t2 = red[1][0][r] + red[1][1][r] + red[1][2][r] + red[1][3][r];
    mu[j] = t1 * (1.0f / 256.0f);
    rstd[j] = rsqrtf(t2 * (1.0f / 256.0f) - mu[j] * mu[j] + 1e-5f);
  }
  // phase C: out = LN2*g2 + b2n
#pragma unroll
  for (int j = 0; j < 4; ++j) {
#pragma unroll
    for (int nf = 0; nf < 4; ++nf) {
      int c = w * 64 + nf * 16 + lr;
      out[(size_t)rows[j] * 256 + c] =
          (acc[nf][j] - mu[j]) * rstd[j] * g2[c] + b2n[c];
    }
  }
}

extern "C" void kernel_launch(void* const* d_in, const int* in_sizes, int n_in,
                              void* d_out, int out_size, void* d_ws, size_t ws_size,
                              hipStream_t stream) {
  (void)in_sizes; (void)n_in; (void)out_size; (void)ws_size;
  const float* x   = (const float*)d_in[0];
  const int*   ei  = (const int*)d_in[1];
  const float* pos = (const float*)d_in[2];
  const float* Wm1 = (const float*)d_in[3];
  const float* bm1 = (const float*)d_in[4];
  const float* Wm2 = (const float*)d_in[5];
  const float* bm2 = (const float*)d_in[6];
  const float* Wq  = (const float*)d_in[7];
  const float* bq  = (const float*)d_in[8];
  const float* Wk  = (const float*)d_in[9];
  const float* bk  = (const float*)d_in[10];
  const float* Wv  = (const float*)d_in[11];
  const float* bv  = (const float*)d_in[12];
  const float* Wp1 = (const float*)d_in[13];
  const float* bp1 = (const float*)d_in[14];
  const float* Wp2 = (const float*)d_in[15];
  const float* bp2 = (const float*)d_in[16];
  const float* g1  = (const float*)d_in[17];
  const float* b1n = (const float*)d_in[18];
  const float* g2  = (const float*)d_in[19];
  const float* b2n = (const float*)d_in[20];

  const size_t ND = (size_t)NN * 256;
  char* p = (char*)d_ws;
  auto alloc = [&](size_t bytes) {
    char* r = p;
    p += (bytes + 255) & ~(size_t)255;
    return r;
  };
  bf16* btbase = (bf16*)alloc(6 * 65536 * sizeof(bf16));
  bf16* xb    = (bf16*)alloc(ND * 2);
  bf16* hb    = (bf16*)alloc(ND * 2);
  u8*   Qf    = (u8*)alloc(ND);
  u8*   Kf    = (u8*)alloc(ND);
  u8*   Vf    = (u8*)alloc(ND);
  bf16* acc1  = (bf16*)alloc(ND * 2);
  bf16* acc2  = (bf16*)alloc(ND * 2);
  float* sattn = (float*)alloc(NN * 4);
  int* deg    = (int*)alloc(NN * 4);
  int* rowptr = (int*)alloc((NN + 1) * 4);
  int* cursor = (int*)alloc(NN * 4);
  int* srcs   = (int*)alloc(NE * 4);

  hipMemsetAsync(deg, 0, NN * 4, stream);

  PrepArgs pa;
  pa.w[0] = Wm1; pa.w[1] = Wm2; pa.w[2] = Wq; pa.w[3] = Wk; pa.w[4] = Wv; pa.w[5] = Wp2;
  for (int i = 0; i < 6; ++i) pa.o[i] = btbase + i * 65536;
  pa.x = x; pa.xb = xb; pa.ei = ei; pa.deg = deg;
  prep_kernel<<<384 + 2500 + (NE + 255) / 256, 256, 0, stream>>>(pa);

  scan_kernel<<<1, 1024, 0, stream>>>(deg, rowptr, cursor);
  scatter_kernel<<<(NE + 255) / 256, 256, 0, stream>>>(ei, cursor, srcs);

  mlpqkv_kernel<<<NN / 16, 256, 0, stream>>>(xb, btbase, bm1, bm2, bq, bk, bv,
                                             hb, Qf, Kf, Vf);

  attn_kernel<<<NN / 4, 256, 0, stream>>>(Qf, Kf, Vf, pos, Wp1, bp1, rowptr, srcs,
                                          acc1, acc2, sattn);

  final_kernel<<<NN / 16, 256, 0, stream>>>(acc2, btbase + 5 * 65536, acc1, sattn,
                                            bp2, hb, x, g1, b1n, g2, b2n,
                                            (float*)d_out);
}

// Round 18
// 144.889 us; speedup vs baseline: 1.4316x; 1.3092x over previous
//
#include <hip/hip_runtime.h>
#include <hip/hip_bf16.h>
#include <math.h>

// AGTBlock. r13 structure + FRAGMENT-MAJOR B/x layout:
//  weights & x stored as contiguous 1KB MFMA fragments ([frag][lane][8 bf16]),
//  so every A/B fragment load is one fully-coalesced 1KB wave-load (16 cache
//  lines vs 64 with row-major 512B-strided lanes).
//  - Wp2 pulled out of the edge sum: node GEMM fused into final.
//  - MLP+QKV fused at 16-row tiles (625 blocks x 4 waves).
//  - attn (r10-proven): fp8 MFMA QK, scalar posMLP, single-pass exp.
//  - final at 16-row blocks: MFMA Wp2 GEMM + 2x LayerNorm.
// launches: memset, prep(fragB+fragX+hist), scan, scatter, mlpqkv, attn, final.

#define NN 10000
#define NE 320000

typedef __bf16 bf16;
typedef __bf16 bf16x8 __attribute__((ext_vector_type(8)));
typedef __bf16 bf16x4 __attribute__((ext_vector_type(4)));
typedef float f32x4 __attribute__((ext_vector_type(4)));
typedef unsigned char u8;

__device__ __forceinline__ float wave_sum(float v) {
#pragma unroll
  for (int off = 32; off; off >>= 1) v += __shfl_xor(v, off, 64);
  return v;
}

// is64 inline detect: high words of first 4 int64 edges are 0 (values < 2^31).
__device__ __forceinline__ int detect64(const int* __restrict__ ei) {
  return (ei[1] | ei[3] | ei[5] | ei[7]) == 0;
}

__device__ __forceinline__ void load_edge(const int* __restrict__ ei, int is64,
                                          int e, int& s, int& dn) {
  if (is64) {
    const long long* e64 = (const long long*)ei;
    s = (int)e64[e];
    dn = (int)e64[NE + e];
  } else {
    s = ei[e];
    dn = ei[NE + e];
  }
  s = min(max(s, 0), NN - 1);
  dn = min(max(dn, 0), NN - 1);
}

// ------- prep: weights+x -> fragment-major bf16, + edge histogram -------
// Fragment f of a matrix covers cols [nf*16,+16) x k [kk*32,+32); within it,
// lane l = (col%16) + 16*((k%32)/8) holds 8 k-contiguous elems at f*512+l*8.
struct PrepArgs { const float* w[6]; bf16* o[6]; const float* x; bf16* xbf;
                  const int* ei; int* deg; };

__global__ __launch_bounds__(256) void prep_kernel(PrepArgs pa) {
  int b = blockIdx.x;
  int w = threadIdx.x >> 6, lane = threadIdx.x & 63;
  int lr = lane & 15, kh = lane >> 4;
  if (b < 192) {  // 6 mats x 128 frags, 1 frag/wave: o[f][l][e] = W[k][n]
    int f = b * 4 + w;               // 0..767
    int mat = f >> 7, fr = f & 127;
    int nfp = fr >> 3, kk = fr & 7;
    const float* ws = pa.w[mat];
    bf16x8 o;
#pragma unroll
    for (int e = 0; e < 8; ++e)
      o[e] = (bf16)ws[(kk * 32 + kh * 8 + e) * 256 + nfp * 16 + lr];
    *(bf16x8*)(pa.o[mat] + (size_t)fr * 512 + lane * 8) = o;
  } else if (b < 192 + 1250) {  // x -> fragment-major bf16 (5000 frags)
    int g = (b - 192) * 4 + w;       // 0..4999
    int rt = g >> 3, kk = g & 7;
    const float* xs = pa.x + (size_t)(rt * 16 + lr) * 256 + kk * 32 + kh * 8;
    float4 a0 = *(const float4*)xs;
    float4 a1 = *(const float4*)(xs + 4);
    bf16x8 o;
    o[0] = (bf16)a0.x; o[1] = (bf16)a0.y; o[2] = (bf16)a0.z; o[3] = (bf16)a0.w;
    o[4] = (bf16)a1.x; o[5] = (bf16)a1.y; o[6] = (bf16)a1.z; o[7] = (bf16)a1.w;
    *(bf16x8*)(pa.xbf + (size_t)g * 512 + lane * 8) = o;
  } else {  // histogram of dst (deg pre-zeroed via memset)
    int is64 = detect64(pa.ei);
    int e = (b - 1442) * 256 + threadIdx.x;
    if (e < NE) {
      int s, dn;
      load_edge(pa.ei, is64, e, s, dn);
      atomicAdd(&pa.deg[dn], 1);
    }
  }
}

__global__ __launch_bounds__(1024) void scan_kernel(
    const int* __restrict__ deg, int* __restrict__ rowptr,
    int* __restrict__ cursor) {
  __shared__ int wsum[16];
  int t = threadIdx.x, wid = t >> 6, lane = t & 63;
  int base = t * 10;
  int v[10];
  int s = 0;
#pragma unroll
  for (int i = 0; i < 10; ++i) {
    int idx = base + i;
    v[i] = (idx < NN) ? deg[idx] : 0;
    s += v[i];
  }
  int x = s;
#pragma unroll
  for (int off = 1; off < 64; off <<= 1) {
    int y = __shfl_up(x, off, 64);
    if (lane >= off) x += y;
  }
  if (lane == 63) wsum[wid] = x;
  __syncthreads();
  if (wid == 0) {
    int ws = (lane < 16) ? wsum[lane] : 0;
#pragma unroll
    for (int off = 1; off < 16; off <<= 1) {
      int y = __shfl_up(ws, off, 64);
      if (lane >= off) ws += y;
    }
    if (lane < 16) wsum[lane] = ws;
  }
  __syncthreads();
  int run = ((wid > 0) ? wsum[wid - 1] : 0) + x - s;  // exclusive prefix
#pragma unroll
  for (int i = 0; i < 10; ++i) {
    int idx = base + i;
    if (idx < NN) {
      cursor[idx] = run;
      run += v[i];
      rowptr[idx + 1] = run;
    }
  }
  if (t == 0) rowptr[0] = 0;
}

__global__ void scatter_kernel(const int* __restrict__ ei,
                               int* __restrict__ cursor, int* __restrict__ srcs) {
  int is64 = detect64(ei);
  int e = blockIdx.x * 256 + threadIdx.x;
  if (e < NE) {
    int s, dn;
    load_edge(ei, is64, e, s, dn);
    int slot = atomicAdd(&cursor[dn], 1);
    if (slot >= 0 && slot < NE) srcs[slot] = s;
  }
}

// ---------------- fused MLP+QKV: 16-row tiles, 625 blocks ----------------
// All A/B fragment loads are contiguous 1KB wave-loads (fragment-major).
#define LP 264

__global__ __launch_bounds__(256) void mlpqkv_kernel(
    const bf16* __restrict__ xbf, const bf16* __restrict__ btf,
    const float* __restrict__ bm1, const float* __restrict__ bm2,
    const float* __restrict__ bq, const float* __restrict__ bk,
    const float* __restrict__ bv, bf16* __restrict__ hb,
    u8* __restrict__ Qf, u8* __restrict__ Kf, u8* __restrict__ Vf) {
  __shared__ bf16 lds[16 * LP];
  int w = threadIdx.x >> 6, lane = threadIdx.x & 63;
  int lr = lane & 15, kh = lane >> 4;
  int rb = blockIdx.x * 16;  // NN = 625*16 exactly
  f32x4 acc[4];
  // stage 1: h1 slice [16 x 64cols(w)] -> LDS; A,B fragment-major
#pragma unroll
  for (int nf = 0; nf < 4; ++nf) acc[nf] = (f32x4){0, 0, 0, 0};
  {
    const bf16* Af = xbf + (size_t)blockIdx.x * 4096;
#pragma unroll
    for (int kk = 0; kk < 8; ++kk) {
      bf16x8 af = *(const bf16x8*)(Af + kk * 512 + lane * 8);
#pragma unroll
      for (int nf = 0; nf < 4; ++nf) {
        bf16x8 bfr = *(const bf16x8*)(btf + (size_t)(((w * 4 + nf) * 8 + kk) * 512) + lane * 8);
        acc[nf] = __builtin_amdgcn_mfma_f32_16x16x32_bf16(af, bfr, acc[nf], 0, 0, 0);
      }
    }
  }
#pragma unroll
  for (int nf = 0; nf < 4; ++nf) {
    int c = w * 64 + nf * 16 + lr;
    float b1 = bm1[c];
#pragma unroll
    for (int j = 0; j < 4; ++j)
      lds[(kh * 4 + j) * LP + c] = (bf16)fmaxf(acc[nf][j] + b1, 0.0f);
  }
  __syncthreads();
  // stage 2: h = h1(LDS) @ Wm2 + bm2 -> LDS + hb
  bf16x8 haf[8];
#pragma unroll
  for (int kk = 0; kk < 8; ++kk)
    haf[kk] = *(const bf16x8*)(lds + lr * LP + kh * 8 + kk * 32);
#pragma unroll
  for (int nf = 0; nf < 4; ++nf) acc[nf] = (f32x4){0, 0, 0, 0};
  {
    const bf16* Bf = btf + 65536;
#pragma unroll
    for (int kk = 0; kk < 8; ++kk) {
#pragma unroll
      for (int nf = 0; nf < 4; ++nf) {
        bf16x8 bfr = *(const bf16x8*)(Bf + (size_t)(((w * 4 + nf) * 8 + kk) * 512) + lane * 8);
        acc[nf] = __builtin_amdgcn_mfma_f32_16x16x32_bf16(haf[kk], bfr, acc[nf], 0, 0, 0);
      }
    }
  }
  __syncthreads();  // h1 reads complete before overwrite
#pragma unroll
  for (int nf = 0; nf < 4; ++nf) {
    int c = w * 64 + nf * 16 + lr;
    float b2 = bm2[c];
#pragma unroll
    for (int j = 0; j < 4; ++j) {
      int r = rb + kh * 4 + j;
      float v = acc[nf][j] + b2;
      lds[(kh * 4 + j) * LP + c] = (bf16)v;
      hb[(size_t)r * 256 + c] = (bf16)v;
    }
  }
  __syncthreads();
  // stage 3: Q,K,V = h(LDS) @ W* + b* -> fp8 (serial segments, r13-proven)
#pragma unroll
  for (int kk = 0; kk < 8; ++kk)
    haf[kk] = *(const bf16x8*)(lds + lr * LP + kh * 8 + kk * 32);
  const float* bias3[3] = {bq, bk, bv};
  u8* out3[3] = {Qf, Kf, Vf};
#pragma unroll
  for (int seg = 0; seg < 3; ++seg) {
#pragma unroll
    for (int nf = 0; nf < 4; ++nf) acc[nf] = (f32x4){0, 0, 0, 0};
    const bf16* Bf = btf + (size_t)(2 + seg) * 65536;
#pragma unroll
    for (int kk = 0; kk < 8; ++kk) {
#pragma unroll
      for (int nf = 0; nf < 4; ++nf) {
        bf16x8 bfr = *(const bf16x8*)(Bf + (size_t)(((w * 4 + nf) * 8 + kk) * 512) + lane * 8);
        acc[nf] = __builtin_amdgcn_mfma_f32_16x16x32_bf16(haf[kk], bfr, acc[nf], 0, 0, 0);
      }
    }
    u8* o = out3[seg];
    const float* bb = bias3[seg];
#pragma unroll
    for (int nf = 0; nf < 4; ++nf) {
      int c = w * 64 + nf * 16 + lr;
      float bx = bb[c];
#pragma unroll
      for (int j = 0; j < 4; ++j) {
        int r = rb + kh * 4 + j;
        float v = acc[nf][j] + bx;
        int pk = __builtin_amdgcn_cvt_pk_fp8_f32(v, v, 0, false);
        o[(size_t)r * 256 + c] = (u8)(pk & 0xff);
      }
    }
  }
}

// ------- per-dst attention (r10-proven): fp8 MFMA QK, scalar posMLP -------
__global__ __launch_bounds__(256) void attn_kernel(
    const u8* __restrict__ Qf, const u8* __restrict__ Kf, const u8* __restrict__ Vf,
    const float* __restrict__ pos, const float* __restrict__ Wp1, const float* __restrict__ bp1,
    const int* __restrict__ rowptr, const int* __restrict__ srcs,
    bf16* __restrict__ acc1, bf16* __restrict__ acc2, float* __restrict__ sattn) {
  int n = blockIdx.x * 4 + (threadIdx.x >> 6);
  int lane = threadIdx.x & 63;
  int lr = lane & 15, kh = lane >> 4;
  int d = lane * 4;
  int e0 = min(max(rowptr[n], 0), NE);
  int e1 = min(max(rowptr[n + 1], e0), NE);
  long long qfr[8];
#pragma unroll
  for (int m = 0; m < 8; ++m)
    qfr[m] = *(const long long*)(Qf + (size_t)n * 256 + m * 32 + kh * 8);
  float px = pos[n * 3], py = pos[n * 3 + 1], pz = pos[n * 3 + 2];
  float w0[4], w1[4], w2[4], bp[4];
#pragma unroll
  for (int j = 0; j < 4; ++j) {
    w0[j] = Wp1[d + j];
    w1[j] = Wp1[256 + d + j];
    w2[j] = Wp1[512 + d + j];
    bp[j] = bp1[d + j];
  }
  float aV[4] = {0, 0, 0, 0}, aP[4] = {0, 0, 0, 0};
  float dpart = 0.0f;
  for (int base = e0; base < e1; base += 16) {
    int sv = srcs[min(base + lr, e1 - 1)];
    f32x4 al = {0.0f, 0.0f, 0.0f, 0.0f};
#pragma unroll
    for (int m = 0; m < 8; ++m) {
      long long kfr = *(const long long*)(Kf + (size_t)sv * 256 + m * 32 + kh * 8);
      al = __builtin_amdgcn_mfma_f32_16x16x32_fp8_fp8(kfr, qfr[m], al, 0, 0, 0);
    }
    float wg[4];
#pragma unroll
    for (int j = 0; j < 4; ++j) {
      int e = base + kh * 4 + j;
      wg[j] = (e < e1) ? __expf(al[j] * 0.0625f) : 0.0f;  // alpha/sqrt(256)
      dpart += wg[j];
    }
#pragma unroll
    for (int ii = 0; ii < 4; ++ii) {
      if (base + ii * 4 < e1) {
#pragma unroll
        for (int j = 0; j < 4; ++j) {
          float we = __int_as_float(
              __builtin_amdgcn_readlane(__float_as_int(wg[j]), ii * 16));
          int se = __builtin_amdgcn_readlane(sv, ii * 4 + j);
          unsigned vw = *(const unsigned*)(Vf + (size_t)se * 256 + lane * 4);
          float vvf[4];
          vvf[0] = __builtin_amdgcn_cvt_f32_fp8(vw, 0);
          vvf[1] = __builtin_amdgcn_cvt_f32_fp8(vw, 1);
          vvf[2] = __builtin_amdgcn_cvt_f32_fp8(vw, 2);
          vvf[3] = __builtin_amdgcn_cvt_f32_fp8(vw, 3);
          float rx = pos[se * 3] - px, ry = pos[se * 3 + 1] - py,
                rz = pos[se * 3 + 2] - pz;
#pragma unroll
          for (int jj = 0; jj < 4; ++jj) {
            float p1 = fmaf(rx, w0[jj], fmaf(ry, w1[jj], fmaf(rz, w2[jj], bp[jj])));
            p1 = fmaxf(p1, 0.0f);
            aV[jj] = fmaf(we, vvf[jj], aV[jj]);
            aP[jj] = fmaf(we, p1, aP[jj]);
          }
        }
      }
    }
  }
  float denom = wave_sum(dpart) * (1.0f / 16.0f);  // each edge replicated x16
  float r = 1.0f / (denom + 1e-16f);
  if (lane == 0) sattn[n] = denom * r;
  bf16x4 o1, o2;
#pragma unroll
  for (int j = 0; j < 4; ++j) {
    o1[j] = (bf16)(aV[j] * r);
    o2[j] = (bf16)(aP[j] * r);
  }
  *(bf16x4*)(acc1 + (size_t)n * 256 + d) = o1;
  *(bf16x4*)(acc2 + (size_t)n * 256 + d) = o2;
}

// ------- final: tmp = acc2@Wp2 (fragment-major B) + residuals + 2x LN -------
__global__ __launch_bounds__(256) void final_kernel(
    const bf16* __restrict__ acc2, const bf16* __restrict__ Bt5,
    const bf16* __restrict__ acc1, const float* __restrict__ sattn,
    const float* __restrict__ bp2, const bf16* __restrict__ hb,
    const float* __restrict__ x, const float* __restrict__ g1,
    const float* __restrict__ b1n, const float* __restrict__ g2,
    const float* __restrict__ b2n, float* __restrict__ out) {
  __shared__ float red[2][4][16];
  int w = threadIdx.x >> 6, lane = threadIdx.x & 63;
  int lr = lane & 15, kh = lane >> 4;
  int rb = blockIdx.x * 16;  // NN = 625*16 exactly
  int arow = rb + lr;
  const bf16* Ap = acc2 + (size_t)arow * 256 + kh * 8;
  f32x4 acc[4];
#pragma unroll
  for (int nf = 0; nf < 4; ++nf) acc[nf] = (f32x4){0, 0, 0, 0};
#pragma unroll
  for (int kk = 0; kk < 8; ++kk) {
    bf16x8 af = *(const bf16x8*)(Ap + kk * 32);
#pragma unroll
    for (int nf = 0; nf < 4; ++nf) {
      bf16x8 bfr = *(const bf16x8*)(Bt5 + (size_t)(((w * 4 + nf) * 8 + kk) * 512) + lane * 8);
      acc[nf] = __builtin_amdgcn_mfma_f32_16x16x32_bf16(af, bfr, acc[nf], 0, 0, 0);
    }
  }
  int rows[4];
  float sr[4];
#pragma unroll
  for (int j = 0; j < 4; ++j) {
    rows[j] = rb + kh * 4 + j;
    sr[j] = sattn[rows[j]];
  }
  // phase A: v = tmp + acc1 + s*bp2 + h ; mean/var via sum & sumsq
  float s1[4] = {0, 0, 0, 0}, s2[4] = {0, 0, 0, 0};
#pragma unroll
  for (int nf = 0; nf < 4; ++nf) {
    int c = w * 64 + nf * 16 + lr;
#pragma unroll
    for (int j = 0; j < 4; ++j) {
      size_t idx = (size_t)rows[j] * 256 + c;
      float v = acc[nf][j] + (float)acc1[idx] + sr[j] * bp2[c] + (float)hb[idx];
      acc[nf][j] = v;
      s1[j] += v;
      s2[j] += v * v;
    }
  }
#pragma unroll
  for (int j = 0; j < 4; ++j) {
#pragma unroll
    for (int off = 1; off < 16; off <<= 1) {
      s1[j] += __shfl_xor(s1[j], off, 64);
      s2[j] += __shfl_xor(s2[j], off, 64);
    }
  }
  if (lr == 0) {
#pragma unroll
    for (int j = 0; j < 4; ++j) {
      red[0][w][kh * 4 + j] = s1[j];
      red[1][w][kh * 4 + j] = s2[j];
    }
  }
  __syncthreads();
  float mu[4], rstd[4];
#pragma unroll
  for (int j = 0; j < 4; ++j) {
    int r = kh * 4 + j;
    float t1 = red[0][0][r] + red[0][1][r] + red[0][2][r] + red[0][3][r];
    float t2 = red[1][0][r] + red[1][1][r] + red[1][2][r] + red[1][3][r];
    mu[j] = t1 * (1.0f / 256.0f);
    rstd[j] = rsqrtf(t2 * (1.0f / 256.0f) - mu[j] * mu[j] + 1e-5f);
  }
  __syncthreads();
  // phase B: u = LN1*g1 + b1n + x ; second mean/var
#pragma unroll
  for (int j = 0; j < 4; ++j) { s1[j] = 0; s2[j] = 0; }
#pragma unroll
  for (int nf = 0; nf < 4; ++nf) {
    int c = w * 64 + nf * 16 + lr;
#pragma unroll
    for (int j = 0; j < 4; ++j) {
      float u = (acc[nf][j] - mu[j]) * rstd[j] * g1[c] + b1n[c] +
                x[(size_t)rows[j] * 256 + c];
      acc[nf][j] = u;
      s1[j] += u;
      s2[j] += u * u;
    }
  }
#pragma unroll
  for (int j = 0; j < 4; ++j) {
#pragma unroll
    for (int off = 1; off < 16; off <<= 1) {
      s1[j] += __shfl_xor(s1[j], off, 64);
      s2[j] += __shfl_xor(s2[j], off, 64);
    }
  }
  if (lr == 0) {
#pragma unroll
    for (int j = 0; j < 4; ++j) {
      red[0][w][kh * 4 + j] = s1[j];
      red[1][w][kh * 4 + j] = s2[j];
    }
  }
  __syncthreads();
#pragma unroll
  for (int j = 0; j < 4; ++j) {
    int r = kh * 4 + j;
    float t1 = red[0][0][r] + red[0][1][r] + red[0][2][r] + red[0][3][r];
    float t2 = red[1][0][r] + red[1][1][r] + red[1][2][r] + red[1][3][r];
    mu[j] = t1 * (1.0f / 256.0f);
    rstd[j] = rsqrtf(t2 * (1.0f / 256.0f) - mu[j] * mu[j] + 1e-5f);
  }
  // phase C: out = LN2*g2 + b2n
#pragma unroll
  for (int j = 0; j < 4; ++j) {
#pragma unroll
    for (int nf = 0; nf < 4; ++nf) {
      int c = w * 64 + nf * 16 + lr;
      out[(size_t)rows[j] * 256 + c] =
          (acc[nf][j] - mu[j]) * rstd[j] * g2[c] + b2n[c];
    }
  }
}

extern "C" void kernel_launch(void* const* d_in, const int* in_sizes, int n_in,
                              void* d_out, int out_size, void* d_ws, size_t ws_size,
                              hipStream_t stream) {
  (void)in_sizes; (void)n_in; (void)out_size; (void)ws_size;
  const float* x   = (const float*)d_in[0];
  const int*   ei  = (const int*)d_in[1];
  const float* pos = (const float*)d_in[2];
  const float* Wm1 = (const float*)d_in[3];
  const float* bm1 = (const float*)d_in[4];
  const float* Wm2 = (const float*)d_in[5];
  const float* bm2 = (const float*)d_in[6];
  const float* Wq  = (const float*)d_in[7];
  const float* bq  = (const float*)d_in[8];
  const float* Wk  = (const float*)d_in[9];
  const float* bk  = (const float*)d_in[10];
  const float* Wv  = (const float*)d_in[11];
  const float* bv  = (const float*)d_in[12];
  const float* Wp1 = (const float*)d_in[13];
  const float* bp1 = (const float*)d_in[14];
  const float* Wp2 = (const float*)d_in[15];
  const float* bp2 = (const float*)d_in[16];
  const float* g1  = (const float*)d_in[17];
  const float* b1n = (const float*)d_in[18];
  const float* g2  = (const float*)d_in[19];
  const float* b2n = (const float*)d_in[20];

  const size_t ND = (size_t)NN * 256;
  char* p = (char*)d_ws;
  auto alloc = [&](size_t bytes) {
    char* r = p;
    p += (bytes + 255) & ~(size_t)255;
    return r;
  };
  bf16* btbase = (bf16*)alloc(6 * 65536 * sizeof(bf16));
  bf16* xbf   = (bf16*)alloc(ND * 2);
  bf16* hb    = (bf16*)alloc(ND * 2);
  u8*   Qf    = (u8*)alloc(ND);
  u8*   Kf    = (u8*)alloc(ND);
  u8*   Vf    = (u8*)alloc(ND);
  bf16* acc1  = (bf16*)alloc(ND * 2);
  bf16* acc2  = (bf16*)alloc(ND * 2);
  float* sattn = (float*)alloc(NN * 4);
  int* deg    = (int*)alloc(NN * 4);
  int* rowptr = (int*)alloc((NN + 1) * 4);
  int* cursor = (int*)alloc(NN * 4);
  int* srcs   = (int*)alloc(NE * 4);

  hipMemsetAsync(deg, 0, NN * 4, stream);

  PrepArgs pa;
  pa.w[0] = Wm1; pa.w[1] = Wm2; pa.w[2] = Wq; pa.w[3] = Wk; pa.w[4] = Wv; pa.w[5] = Wp2;
  for (int i = 0; i < 6; ++i) pa.o[i] = btbase + i * 65536;
  pa.x = x; pa.xbf = xbf; pa.ei = ei; pa.deg = deg;
  prep_kernel<<<192 + 1250 + (NE + 255) / 256, 256, 0, stream>>>(pa);

  scan_kernel<<<1, 1024, 0, stream>>>(deg, rowptr, cursor);
  scatter_kernel<<<(NE + 255) / 256, 256, 0, stream>>>(ei, cursor, srcs);

  mlpqkv_kernel<<<NN / 16, 256, 0, stream>>>(xbf, btbase, bm1, bm2, bq, bk, bv,
                                             hb, Qf, Kf, Vf);

  attn_kernel<<<NN / 4, 256, 0, stream>>>(Qf, Kf, Vf, pos, Wp1, bp1, rowptr, srcs,
                                          acc1, acc2, sattn);

  final_kernel<<<NN / 16, 256, 0, stream>>>(acc2, btbase + 5 * 65536, acc1, sattn,
                                            bp2, hb, x, g1, b1n, g2, b2n,
                                            (float*)d_out);
}

// Round 19
// 140.834 us; speedup vs baseline: 1.4728x; 1.0288x over previous
//
#include <hip/hip_runtime.h>
#include <hip/hip_bf16.h>
#include <math.h>

// AGTBlock. r18 (fragment-major) + single-gather attention:
//  alpha = Q·K = (Q@Wk^T)·h_src + const(dst)  -> Qm = Q@Wk-rows, gather only h.
//  Sum attn·V = (Sum attn·h)@Wv + (Sum attn)·bv  -> Wv GEMM fused into final.
//  Gathered fp8 h row serves BOTH the alpha MFMA and the weighted accumulation.
//  - MLP+QKV->h,Q,Qm chain fused at 16-row tiles (625 blocks x 4 waves).
//  - attn: fp8 MFMA alpha, scalar posMLP, single-pass exp (shift-invariant).
//  - final: dual GEMM accH@Wv + accP@Wp2 + 2x LayerNorm.
// Scales: Hf = fp8(8h), Qmf = fp8(512*Qm); exp uses al/65536 (=alpha/16).
// launches: memset, prep(frags+hist), scan, scatter, mlpqkv, attn, final.

#define NN 10000
#define NE 320000

typedef __bf16 bf16;
typedef __bf16 bf16x8 __attribute__((ext_vector_type(8)));
typedef __bf16 bf16x4 __attribute__((ext_vector_type(4)));
typedef float f32x4 __attribute__((ext_vector_type(4)));
typedef unsigned char u8;

__device__ __forceinline__ float wave_sum(float v) {
#pragma unroll
  for (int off = 32; off; off >>= 1) v += __shfl_xor(v, off, 64);
  return v;
}

__device__ __forceinline__ int detect64(const int* __restrict__ ei) {
  return (ei[1] | ei[3] | ei[5] | ei[7]) == 0;
}

__device__ __forceinline__ void load_edge(const int* __restrict__ ei, int is64,
                                          int e, int& s, int& dn) {
  if (is64) {
    const long long* e64 = (const long long*)ei;
    s = (int)e64[e];
    dn = (int)e64[NE + e];
  } else {
    s = ei[e];
    dn = ei[NE + e];
  }
  s = min(max(s, 0), NN - 1);
  dn = min(max(dn, 0), NN - 1);
}

// ------- prep: weights+x -> fragment-major bf16, + edge histogram -------
// mats 0,1,2,4,5 transposed (B[n][k]=W[k][n]); mat 3 = Wk NON-transposed
// (B[b][d]=Wk[b][d], for Qm = Q @ Wk-rows contraction over d).
struct PrepArgs { const float* w[6]; bf16* o[6]; const float* x; bf16* xbf;
                  const int* ei; int* deg; };

__global__ __launch_bounds__(256) void prep_kernel(PrepArgs pa) {
  int b = blockIdx.x;
  int w = threadIdx.x >> 6, lane = threadIdx.x & 63;
  int lr = lane & 15, kh = lane >> 4;
  if (b < 192) {  // 6 mats x 128 frags, 1 frag/wave
    int f = b * 4 + w;
    int mat = f >> 7, fr = f & 127;
    int nfp = fr >> 3, kk = fr & 7;
    const float* ws = pa.w[mat];
    bf16x8 o;
    if (mat == 3) {  // Wk rows: contiguous reads
      const float* s = ws + (size_t)(nfp * 16 + lr) * 256 + kk * 32 + kh * 8;
      float4 a0 = *(const float4*)s;
      float4 a1 = *(const float4*)(s + 4);
      o[0] = (bf16)a0.x; o[1] = (bf16)a0.y; o[2] = (bf16)a0.z; o[3] = (bf16)a0.w;
      o[4] = (bf16)a1.x; o[5] = (bf16)a1.y; o[6] = (bf16)a1.z; o[7] = (bf16)a1.w;
    } else {
#pragma unroll
      for (int e = 0; e < 8; ++e)
        o[e] = (bf16)ws[(kk * 32 + kh * 8 + e) * 256 + nfp * 16 + lr];
    }
    *(bf16x8*)(pa.o[mat] + (size_t)fr * 512 + lane * 8) = o;
  } else if (b < 192 + 1250) {  // x -> fragment-major bf16 (5000 frags)
    int g = (b - 192) * 4 + w;
    int rt = g >> 3, kk = g & 7;
    const float* xs = pa.x + (size_t)(rt * 16 + lr) * 256 + kk * 32 + kh * 8;
    float4 a0 = *(const float4*)xs;
    float4 a1 = *(const float4*)(xs + 4);
    bf16x8 o;
    o[0] = (bf16)a0.x; o[1] = (bf16)a0.y; o[2] = (bf16)a0.z; o[3] = (bf16)a0.w;
    o[4] = (bf16)a1.x; o[5] = (bf16)a1.y; o[6] = (bf16)a1.z; o[7] = (bf16)a1.w;
    *(bf16x8*)(pa.xbf + (size_t)g * 512 + lane * 8) = o;
  } else {  // histogram of dst (deg pre-zeroed via memset)
    int is64 = detect64(pa.ei);
    int e = (b - 1442) * 256 + threadIdx.x;
    if (e < NE) {
      int s, dn;
      load_edge(pa.ei, is64, e, s, dn);
      atomicAdd(&pa.deg[dn], 1);
    }
  }
}

__global__ __launch_bounds__(1024) void scan_kernel(
    const int* __restrict__ deg, int* __restrict__ rowptr,
    int* __restrict__ cursor) {
  __shared__ int wsum[16];
  int t = threadIdx.x, wid = t >> 6, lane = t & 63;
  int base = t * 10;
  int v[10];
  int s = 0;
#pragma unroll
  for (int i = 0; i < 10; ++i) {
    int idx = base + i;
    v[i] = (idx < NN) ? deg[idx] : 0;
    s += v[i];
  }
  int x = s;
#pragma unroll
  for (int off = 1; off < 64; off <<= 1) {
    int y = __shfl_up(x, off, 64);
    if (lane >= off) x += y;
  }
  if (lane == 63) wsum[wid] = x;
  __syncthreads();
  if (wid == 0) {
    int ws = (lane < 16) ? wsum[lane] : 0;
#pragma unroll
    for (int off = 1; off < 16; off <<= 1) {
      int y = __shfl_up(ws, off, 64);
      if (lane >= off) ws += y;
    }
    if (lane < 16) wsum[lane] = ws;
  }
  __syncthreads();
  int run = ((wid > 0) ? wsum[wid - 1] : 0) + x - s;  // exclusive prefix
#pragma unroll
  for (int i = 0; i < 10; ++i) {
    int idx = base + i;
    if (idx < NN) {
      cursor[idx] = run;
      run += v[i];
      rowptr[idx + 1] = run;
    }
  }
  if (t == 0) rowptr[0] = 0;
}

__global__ void scatter_kernel(const int* __restrict__ ei,
                               int* __restrict__ cursor, int* __restrict__ srcs) {
  int is64 = detect64(ei);
  int e = blockIdx.x * 256 + threadIdx.x;
  if (e < NE) {
    int s, dn;
    load_edge(ei, is64, e, s, dn);
    int slot = atomicAdd(&cursor[dn], 1);
    if (slot >= 0 && slot < NE) srcs[slot] = s;
  }
}

// ---- fused node chain x->h1->h->Q->Qm: 16-row tiles, 625 blocks ----
#define LP 264

__global__ __launch_bounds__(256) void mlpqkv_kernel(
    const bf16* __restrict__ xbf, const bf16* __restrict__ btf,
    const float* __restrict__ bm1, const float* __restrict__ bm2,
    const float* __restrict__ bq, bf16* __restrict__ hb,
    u8* __restrict__ Hf, u8* __restrict__ Qmf) {
  __shared__ bf16 lds[16 * LP];
  int w = threadIdx.x >> 6, lane = threadIdx.x & 63;
  int lr = lane & 15, kh = lane >> 4;
  int rb = blockIdx.x * 16;  // NN = 625*16 exactly
  f32x4 acc[4];
  // stage 1: h1 = relu(x@Wm1+bm1) -> LDS
#pragma unroll
  for (int nf = 0; nf < 4; ++nf) acc[nf] = (f32x4){0, 0, 0, 0};
  {
    const bf16* Af = xbf + (size_t)blockIdx.x * 4096;
#pragma unroll
    for (int kk = 0; kk < 8; ++kk) {
      bf16x8 af = *(const bf16x8*)(Af + kk * 512 + lane * 8);
#pragma unroll
      for (int nf = 0; nf < 4; ++nf) {
        bf16x8 bfr = *(const bf16x8*)(btf + (size_t)(((w * 4 + nf) * 8 + kk) * 512) + lane * 8);
        acc[nf] = __builtin_amdgcn_mfma_f32_16x16x32_bf16(af, bfr, acc[nf], 0, 0, 0);
      }
    }
  }
#pragma unroll
  for (int nf = 0; nf < 4; ++nf) {
    int c = w * 64 + nf * 16 + lr;
    float b1 = bm1[c];
#pragma unroll
    for (int j = 0; j < 4; ++j)
      lds[(kh * 4 + j) * LP + c] = (bf16)fmaxf(acc[nf][j] + b1, 0.0f);
  }
  __syncthreads();
  // stage 2: h = h1(LDS)@Wm2+bm2 -> LDS + hb(bf16) + Hf(fp8 8h)
  bf16x8 haf[8];
#pragma unroll
  for (int kk = 0; kk < 8; ++kk)
    haf[kk] = *(const bf16x8*)(lds + lr * LP + kh * 8 + kk * 32);
#pragma unroll
  for (int nf = 0; nf < 4; ++nf) acc[nf] = (f32x4){0, 0, 0, 0};
  {
    const bf16* Bf = btf + 65536;
#pragma unroll
    for (int kk = 0; kk < 8; ++kk) {
#pragma unroll
      for (int nf = 0; nf < 4; ++nf) {
        bf16x8 bfr = *(const bf16x8*)(Bf + (size_t)(((w * 4 + nf) * 8 + kk) * 512) + lane * 8);
        acc[nf] = __builtin_amdgcn_mfma_f32_16x16x32_bf16(haf[kk], bfr, acc[nf], 0, 0, 0);
      }
    }
  }
  __syncthreads();  // h1 reads complete before overwrite
#pragma unroll
  for (int nf = 0; nf < 4; ++nf) {
    int c = w * 64 + nf * 16 + lr;
    float b2 = bm2[c];
#pragma unroll
    for (int j = 0; j < 4; ++j) {
      int r = rb + kh * 4 + j;
      float v = acc[nf][j] + b2;
      lds[(kh * 4 + j) * LP + c] = (bf16)v;
      hb[(size_t)r * 256 + c] = (bf16)v;
      int pk = __builtin_amdgcn_cvt_pk_fp8_f32(v * 8.0f, v * 8.0f, 0, false);
      Hf[(size_t)r * 256 + c] = (u8)(pk & 0xff);
    }
  }
  __syncthreads();
  // stage 3: Q = h(LDS)@Wq+bq -> LDS
#pragma unroll
  for (int kk = 0; kk < 8; ++kk)
    haf[kk] = *(const bf16x8*)(lds + lr * LP + kh * 8 + kk * 32);
#pragma unroll
  for (int nf = 0; nf < 4; ++nf) acc[nf] = (f32x4){0, 0, 0, 0};
  {
    const bf16* Bf = btf + 2 * 65536;
#pragma unroll
    for (int kk = 0; kk < 8; ++kk) {
#pragma unroll
      for (int nf = 0; nf < 4; ++nf) {
        bf16x8 bfr = *(const bf16x8*)(Bf + (size_t)(((w * 4 + nf) * 8 + kk) * 512) + lane * 8);
        acc[nf] = __builtin_amdgcn_mfma_f32_16x16x32_bf16(haf[kk], bfr, acc[nf], 0, 0, 0);
      }
    }
  }
  __syncthreads();  // h reads complete before overwrite
#pragma unroll
  for (int nf = 0; nf < 4; ++nf) {
    int c = w * 64 + nf * 16 + lr;
    float bx = bq[c];
#pragma unroll
    for (int j = 0; j < 4; ++j)
      lds[(kh * 4 + j) * LP + c] = (bf16)(acc[nf][j] + bx);
  }
  __syncthreads();
  // stage 4: Qm = Q(LDS) @ Wk-rows (no bias; per-dst consts cancel in softmax)
#pragma unroll
  for (int kk = 0; kk < 8; ++kk)
    haf[kk] = *(const bf16x8*)(lds + lr * LP + kh * 8 + kk * 32);
#pragma unroll
  for (int nf = 0; nf < 4; ++nf) acc[nf] = (f32x4){0, 0, 0, 0};
  {
    const bf16* Bf = btf + 3 * 65536;
#pragma unroll
    for (int kk = 0; kk < 8; ++kk) {
#pragma unroll
      for (int nf = 0; nf < 4; ++nf) {
        bf16x8 bfr = *(const bf16x8*)(Bf + (size_t)(((w * 4 + nf) * 8 + kk) * 512) + lane * 8);
        acc[nf] = __builtin_amdgcn_mfma_f32_16x16x32_bf16(haf[kk], bfr, acc[nf], 0, 0, 0);
      }
    }
  }
#pragma unroll
  for (int nf = 0; nf < 4; ++nf) {
    int c = w * 64 + nf * 16 + lr;
#pragma unroll
    for (int j = 0; j < 4; ++j) {
      int r = rb + kh * 4 + j;
      float v = acc[nf][j] * 512.0f;
      int pk = __builtin_amdgcn_cvt_pk_fp8_f32(v, v, 0, false);
      Qmf[(size_t)r * 256 + c] = (u8)(pk & 0xff);
    }
  }
}

// ------- per-dst attention: single h-gather; fp8 MFMA alpha; scalar posMLP -------
__global__ __launch_bounds__(256) void attn_kernel(
    const u8* __restrict__ Qmf, const u8* __restrict__ Hf,
    const float* __restrict__ pos, const float* __restrict__ Wp1, const float* __restrict__ bp1,
    const int* __restrict__ rowptr, const int* __restrict__ srcs,
    bf16* __restrict__ accH, bf16* __restrict__ acc2, float* __restrict__ sattn) {
  int n = blockIdx.x * 4 + (threadIdx.x >> 6);
  int lane = threadIdx.x & 63;
  int lr = lane & 15, kh = lane >> 4;
  int d = lane * 4;
  int e0 = min(max(rowptr[n], 0), NE);
  int e1 = min(max(rowptr[n + 1], e0), NE);
  long long qfr[8];
#pragma unroll
  for (int m = 0; m < 8; ++m)
    qfr[m] = *(const long long*)(Qmf + (size_t)n * 256 + m * 32 + kh * 8);
  float px = pos[n * 3], py = pos[n * 3 + 1], pz = pos[n * 3 + 2];
  float w0[4], w1[4], w2[4], bp[4];
#pragma unroll
  for (int j = 0; j < 4; ++j) {
    w0[j] = Wp1[d + j];
    w1[j] = Wp1[256 + d + j];
    w2[j] = Wp1[512 + d + j];
    bp[j] = bp1[d + j];
  }
  float aV[4] = {0, 0, 0, 0}, aP[4] = {0, 0, 0, 0};
  float dpart = 0.0f;
  for (int base = e0; base < e1; base += 16) {
    int sv = srcs[min(base + lr, e1 - 1)];
    f32x4 al = {0.0f, 0.0f, 0.0f, 0.0f};
#pragma unroll
    for (int m = 0; m < 8; ++m) {
      long long hfr = *(const long long*)(Hf + (size_t)sv * 256 + m * 32 + kh * 8);
      al = __builtin_amdgcn_mfma_f32_16x16x32_fp8_fp8(hfr, qfr[m], al, 0, 0, 0);
    }
    float wg[4];
#pragma unroll
    for (int j = 0; j < 4; ++j) {
      int e = base + kh * 4 + j;
      // al = (512 Qm)·(8 h) = 4096 alpha; alpha/16 = al/65536
      wg[j] = (e < e1) ? __expf(al[j] * 1.52587890625e-05f) : 0.0f;
      dpart += wg[j];
    }
#pragma unroll
    for (int ii = 0; ii < 4; ++ii) {
      if (base + ii * 4 < e1) {
#pragma unroll
        for (int j = 0; j < 4; ++j) {
          float we = __int_as_float(
              __builtin_amdgcn_readlane(__float_as_int(wg[j]), ii * 16));
          int se = __builtin_amdgcn_readlane(sv, ii * 4 + j);
          unsigned vw = *(const unsigned*)(Hf + (size_t)se * 256 + lane * 4);
          float vvf[4];
          vvf[0] = __builtin_amdgcn_cvt_f32_fp8(vw, 0);
          vvf[1] = __builtin_amdgcn_cvt_f32_fp8(vw, 1);
          vvf[2] = __builtin_amdgcn_cvt_f32_fp8(vw, 2);
          vvf[3] = __builtin_amdgcn_cvt_f32_fp8(vw, 3);
          float rx = pos[se * 3] - px, ry = pos[se * 3 + 1] - py,
                rz = pos[se * 3 + 2] - pz;
#pragma unroll
          for (int jj = 0; jj < 4; ++jj) {
            float p1 = fmaf(rx, w0[jj], fmaf(ry, w1[jj], fmaf(rz, w2[jj], bp[jj])));
            p1 = fmaxf(p1, 0.0f);
            aV[jj] = fmaf(we, vvf[jj], aV[jj]);  // accumulates 8*h
            aP[jj] = fmaf(we, p1, aP[jj]);
          }
        }
      }
    }
  }
  float denom = wave_sum(dpart) * (1.0f / 16.0f);  // each edge replicated x16
  float r = 1.0f / (denom + 1e-16f);
  if (lane == 0) sattn[n] = denom * r;
  bf16x4 o1, o2;
#pragma unroll
  for (int j = 0; j < 4; ++j) {
    o1[j] = (bf16)(aV[j] * r * 0.125f);  // undo 8x h scale
    o2[j] = (bf16)(aP[j] * r);
  }
  *(bf16x4*)(accH + (size_t)n * 256 + d) = o1;
  *(bf16x4*)(acc2 + (size_t)n * 256 + d) = o2;
}

// ---- final: accH@Wv + acc2@Wp2 (fragment-major B) + residuals + 2x LN ----
__global__ __launch_bounds__(256) void final_kernel(
    const bf16* __restrict__ accH, const bf16* __restrict__ acc2,
    const bf16* __restrict__ BtWv, const bf16* __restrict__ BtWp2,
    const float* __restrict__ sattn, const float* __restrict__ bv,
    const float* __restrict__ bp2, const bf16* __restrict__ hb,
    const float* __restrict__ x, const float* __restrict__ g1,
    const float* __restrict__ b1n, const float* __restrict__ g2,
    const float* __restrict__ b2n, float* __restrict__ out) {
  __shared__ float red[2][4][16];
  int w = threadIdx.x >> 6, lane = threadIdx.x & 63;
  int lr = lane & 15, kh = lane >> 4;
  int rb = blockIdx.x * 16;  // NN = 625*16 exactly
  int arow = rb + lr;
  const bf16* ApH = accH + (size_t)arow * 256 + kh * 8;
  const bf16* ApP = acc2 + (size_t)arow * 256 + kh * 8;
  f32x4 acc[4];
#pragma unroll
  for (int nf = 0; nf < 4; ++nf) acc[nf] = (f32x4){0, 0, 0, 0};
#pragma unroll
  for (int kk = 0; kk < 8; ++kk) {
    bf16x8 afH = *(const bf16x8*)(ApH + kk * 32);
    bf16x8 afP = *(const bf16x8*)(ApP + kk * 32);
#pragma unroll
    for (int nf = 0; nf < 4; ++nf) {
      bf16x8 b1f = *(const bf16x8*)(BtWv + (size_t)(((w * 4 + nf) * 8 + kk) * 512) + lane * 8);
      acc[nf] = __builtin_amdgcn_mfma_f32_16x16x32_bf16(afH, b1f, acc[nf], 0, 0, 0);
      bf16x8 b2f = *(const bf16x8*)(BtWp2 + (size_t)(((w * 4 + nf) * 8 + kk) * 512) + lane * 8);
      acc[nf] = __builtin_amdgcn_mfma_f32_16x16x32_bf16(afP, b2f, acc[nf], 0, 0, 0);
    }
  }
  int rows[4];
  float sr[4];
#pragma unroll
  for (int j = 0; j < 4; ++j) {
    rows[j] = rb + kh * 4 + j;
    sr[j] = sattn[rows[j]];
  }
  // phase A: v = GEMMs + s*(bv+bp2) + h ; mean/var via sum & sumsq
  float s1[4] = {0, 0, 0, 0}, s2[4] = {0, 0, 0, 0};
#pragma unroll
  for (int nf = 0; nf < 4; ++nf) {
    int c = w * 64 + nf * 16 + lr;
    float bb = bv[c] + bp2[c];
#pragma unroll
    for (int j = 0; j < 4; ++j) {
      size_t idx = (size_t)rows[j] * 256 + c;
      float v = acc[nf][j] + sr[j] * bb + (float)hb[idx];
      acc[nf][j] = v;
      s1[j] += v;
      s2[j] += v * v;
    }
  }
#pragma unroll
  for (int j = 0; j < 4; ++j) {
#pragma unroll
    for (int off = 1; off < 16; off <<= 1) {
      s1[j] += __shfl_xor(s1[j], off, 64);
      s2[j] += __shfl_xor(s2[j], off, 64);
    }
  }
  if (lr == 0) {
#pragma unroll
    for (int j = 0; j < 4; ++j) {
      red[0][w][kh * 4 + j] = s1[j];
      red[1][w][kh * 4 + j] = s2[j];
    }
  }
  __syncthreads();
  float mu[4], rstd[4];
#pragma unroll
  for (int j = 0; j < 4; ++j) {
    int r = kh * 4 + j;
    float t1 = red[0][0][r] + red[0][1][r] + red[0][2][r] + red[0][3][r];
    float t2 = red[1][0][r] + red[1][1][r] + red[1][2][r] + red[1][3][r];
    mu[j] = t1 * (1.0f / 256.0f);
    rstd[j] = rsqrtf(t2 * (1.0f / 256.0f) - mu[j] * mu[j] + 1e-5f);
  }
  __syncthreads();
  // phase B: u = LN1*g1 + b1n + x ; second mean/var
#pragma unroll
  for (int j = 0; j < 4; ++j) { s1[j] = 0; s2[j] = 0; }
#pragma unroll
  for (int nf = 0; nf < 4; ++nf) {
    int c = w * 64 + nf * 16 + lr;
#pragma unroll
    for (int j = 0; j < 4; ++j) {
      float u = (acc[nf][j] - mu[j]) * rstd[j] * g1[c] + b1n[c] +
                x[(size_t)rows[j] * 256 + c];
      acc[nf][j] = u;
      s1[j] += u;
      s2[j] += u * u;
    }
  }
#pragma unroll
  for (int j = 0; j < 4; ++j) {
#pragma unroll
    for (int off = 1; off < 16; off <<= 1) {
      s1[j] += __shfl_xor(s1[j], off, 64);
      s2[j] += __shfl_xor(s2[j], off, 64);
    }
  }
  if (lr == 0) {
#pragma unroll
    for (int j = 0; j < 4; ++j) {
      red[0][w][kh * 4 + j] = s1[j];
      red[1][w][kh * 4 + j] = s2[j];
    }
  }
  __syncthreads();
#pragma unroll
  for (int j = 0; j < 4; ++j) {
    int r = kh * 4 + j;
    float t1 = red[0][0][r] + red[0][1][r] + red[0][2][r] + red[0][3][r];
    float t2 = red[1][0][r] + red[1][1][r] + red[1][2][r] + red[1][3][r];
    mu[j] = t1 * (1.0f / 256.0f);
    rstd[j] = rsqrtf(t2 * (1.0f / 256.0f) - mu[j] * mu[j] + 1e-5f);
  }
  // phase C: out = LN2*g2 + b2n
#pragma unroll
  for (int j = 0; j < 4; ++j) {
#pragma unroll
    for (int nf = 0; nf < 4; ++nf) {
      int c = w * 64 + nf * 16 + lr;
      out[(size_t)rows[j] * 256 + c] =
          (acc[nf][j] - mu[j]) * rstd[j] * g2[c] + b2n[c];
    }
  }
}

extern "C" void kernel_launch(void* const* d_in, const int* in_sizes, int n_in,
                              void* d_out, int out_size, void* d_ws, size_t ws_size,
                              hipStream_t stream) {
  (void)in_sizes; (void)n_in; (void)out_size; (void)ws_size;
  const float* x   = (const float*)d_in[0];
  const int*   ei  = (const int*)d_in[1];
  const float* pos = (const float*)d_in[2];
  const float* Wm1 = (const float*)d_in[3];
  const float* bm1 = (const float*)d_in[4];
  const float* Wm2 = (const float*)d_in[5];
  const float* bm2 = (const float*)d_in[6];
  const float* Wq  = (const float*)d_in[7];
  const float* bq  = (const float*)d_in[8];
  const float* Wk  = (const float*)d_in[9];
  const float* bk  = (const float*)d_in[10];
  const float* Wv  = (const float*)d_in[11];
  const float* bv  = (const float*)d_in[12];
  const float* Wp1 = (const float*)d_in[13];
  const float* bp1 = (const float*)d_in[14];
  const float* Wp2 = (const float*)d_in[15];
  const float* bp2 = (const float*)d_in[16];
  const float* g1  = (const float*)d_in[17];
  const float* b1n = (const float*)d_in[18];
  const float* g2  = (const float*)d_in[19];
  const float* b2n = (const float*)d_in[20];
  (void)bk;  // per-dst const Q·bk cancels in segment softmax

  const size_t ND = (size_t)NN * 256;
  char* p = (char*)d_ws;
  auto alloc = [&](size_t bytes) {
    char* r = p;
    p += (bytes + 255) & ~(size_t)255;
    return r;
  };
  bf16* btbase = (bf16*)alloc(6 * 65536 * sizeof(bf16));
  bf16* xbf   = (bf16*)alloc(ND * 2);
  bf16* hb    = (bf16*)alloc(ND * 2);
  u8*   Hf    = (u8*)alloc(ND);
  u8*   Qmf   = (u8*)alloc(ND);
  bf16* accH  = (bf16*)alloc(ND * 2);
  bf16* acc2  = (bf16*)alloc(ND * 2);
  float* sattn = (float*)alloc(NN * 4);
  int* deg    = (int*)alloc(NN * 4);
  int* rowptr = (int*)alloc((NN + 1) * 4);
  int* cursor = (int*)alloc(NN * 4);
  int* srcs   = (int*)alloc(NE * 4);

  hipMemsetAsync(deg, 0, NN * 4, stream);

  PrepArgs pa;
  pa.w[0] = Wm1; pa.w[1] = Wm2; pa.w[2] = Wq; pa.w[3] = Wk; pa.w[4] = Wv; pa.w[5] = Wp2;
  for (int i = 0; i < 6; ++i) pa.o[i] = btbase + i * 65536;
  pa.x = x; pa.xbf = xbf; pa.ei = ei; pa.deg = deg;
  prep_kernel<<<192 + 1250 + (NE + 255) / 256, 256, 0, stream>>>(pa);

  scan_kernel<<<1, 1024, 0, stream>>>(deg, rowptr, cursor);
  scatter_kernel<<<(NE + 255) / 256, 256, 0, stream>>>(ei, cursor, srcs);

  mlpqkv_kernel<<<NN / 16, 256, 0, stream>>>(xbf, btbase, bm1, bm2, bq, hb, Hf, Qmf);

  attn_kernel<<<NN / 4, 256, 0, stream>>>(Qmf, Hf, pos, Wp1, bp1, rowptr, srcs,
                                          accH, acc2, sattn);

  final_kernel<<<NN / 16, 256, 0, stream>>>(accH, acc2, btbase + 4 * 65536,
                                            btbase + 5 * 65536, sattn, bv, bp2,
                                            hb, x, g1, b1n, g2, b2n,
                                            (float*)d_out);
}

// Round 22
// 135.616 us; speedup vs baseline: 1.5295x; 1.0385x over previous
//
#include <hip/hip_runtime.h>
#include <hip/hip_bf16.h>
#include <math.h>

// AGTBlock. r19 (proven 140.8us) + scatter merged into mlpqkv launch.
//  alpha = Q·K = (Q@Wk^T)·h_src + const(dst) -> Qm = Q@Wk-rows; gather only h.
//  Sum attn·V = (Sum attn·h)@Wv + (Sum attn)·bv -> Wv GEMM fused into final.
//  Fragment-major weights/x (1KB coalesced MFMA fragment loads).
// launches: memset, prep(frags+hist), scan, mlpqkv+scatter, attn, final.

#define NN 10000
#define NE 320000

typedef __bf16 bf16;
typedef __bf16 bf16x8 __attribute__((ext_vector_type(8)));
typedef __bf16 bf16x4 __attribute__((ext_vector_type(4)));
typedef float f32x4 __attribute__((ext_vector_type(4)));
typedef unsigned char u8;

__device__ __forceinline__ float wave_sum(float v) {
#pragma unroll
  for (int off = 32; off; off >>= 1) v += __shfl_xor(v, off, 64);
  return v;
}

__device__ __forceinline__ int detect64(const int* __restrict__ ei) {
  return (ei[1] | ei[3] | ei[5] | ei[7]) == 0;
}

__device__ __forceinline__ void load_edge(const int* __restrict__ ei, int is64,
                                          int e, int& s, int& dn) {
  if (is64) {
    const long long* e64 = (const long long*)ei;
    s = (int)e64[e];
    dn = (int)e64[NE + e];
  } else {
    s = ei[e];
    dn = ei[NE + e];
  }
  s = min(max(s, 0), NN - 1);
  dn = min(max(dn, 0), NN - 1);
}

// ------- prep: weights+x -> fragment-major bf16, + edge histogram -------
// mats 0,1,2,4,5 transposed (B[n][k]=W[k][n]); mat 3 = Wk NON-transposed.
struct PrepArgs { const float* w[6]; bf16* o[6]; const float* x; bf16* xbf;
                  const int* ei; int* deg; };

__global__ __launch_bounds__(256) void prep_kernel(PrepArgs pa) {
  int b = blockIdx.x;
  int w = threadIdx.x >> 6, lane = threadIdx.x & 63;
  int lr = lane & 15, kh = lane >> 4;
  if (b < 192) {  // 6 mats x 128 frags, 1 frag/wave
    int f = b * 4 + w;
    int mat = f >> 7, fr = f & 127;
    int nfp = fr >> 3, kk = fr & 7;
    const float* ws = pa.w[mat];
    bf16x8 o;
    if (mat == 3) {  // Wk rows: contiguous reads
      const float* s = ws + (size_t)(nfp * 16 + lr) * 256 + kk * 32 + kh * 8;
      float4 a0 = *(const float4*)s;
      float4 a1 = *(const float4*)(s + 4);
      o[0] = (bf16)a0.x; o[1] = (bf16)a0.y; o[2] = (bf16)a0.z; o[3] = (bf16)a0.w;
      o[4] = (bf16)a1.x; o[5] = (bf16)a1.y; o[6] = (bf16)a1.z; o[7] = (bf16)a1.w;
    } else {
#pragma unroll
      for (int e = 0; e < 8; ++e)
        o[e] = (bf16)ws[(kk * 32 + kh * 8 + e) * 256 + nfp * 16 + lr];
    }
    *(bf16x8*)(pa.o[mat] + (size_t)fr * 512 + lane * 8) = o;
  } else if (b < 192 + 1250) {  // x -> fragment-major bf16 (5000 frags)
    int g = (b - 192) * 4 + w;
    int rt = g >> 3, kk = g & 7;
    const float* xs = pa.x + (size_t)(rt * 16 + lr) * 256 + kk * 32 + kh * 8;
    float4 a0 = *(const float4*)xs;
    float4 a1 = *(const float4*)(xs + 4);
    bf16x8 o;
    o[0] = (bf16)a0.x; o[1] = (bf16)a0.y; o[2] = (bf16)a0.z; o[3] = (bf16)a0.w;
    o[4] = (bf16)a1.x; o[5] = (bf16)a1.y; o[6] = (bf16)a1.z; o[7] = (bf16)a1.w;
    *(bf16x8*)(pa.xbf + (size_t)g * 512 + lane * 8) = o;
  } else {  // histogram of dst (deg pre-zeroed via memset)
    int is64 = detect64(pa.ei);
    int e = (b - 1442) * 256 + threadIdx.x;
    if (e < NE) {
      int s, dn;
      load_edge(pa.ei, is64, e, s, dn);
      atomicAdd(&pa.deg[dn], 1);
    }
  }
}

__global__ __launch_bounds__(1024) void scan_kernel(
    const int* __restrict__ deg, int* __restrict__ rowptr,
    int* __restrict__ cursor) {
  __shared__ int wsum[16];
  int t = threadIdx.x, wid = t >> 6, lane = t & 63;
  int base = t * 10;
  int v[10];
  int s = 0;
#pragma unroll
  for (int i = 0; i < 10; ++i) {
    int idx = base + i;
    v[i] = (idx < NN) ? deg[idx] : 0;
    s += v[i];
  }
  int x = s;
#pragma unroll
  for (int off = 1; off < 64; off <<= 1) {
    int y = __shfl_up(x, off, 64);
    if (lane >= off) x += y;
  }
  if (lane == 63) wsum[wid] = x;
  __syncthreads();
  if (wid == 0) {
    int ws = (lane < 16) ? wsum[lane] : 0;
#pragma unroll
    for (int off = 1; off < 16; off <<= 1) {
      int y = __shfl_up(ws, off, 64);
      if (lane >= off) ws += y;
    }
    if (lane < 16) wsum[lane] = ws;
  }
  __syncthreads();
  int run = ((wid > 0) ? wsum[wid - 1] : 0) + x - s;  // exclusive prefix
#pragma unroll
  for (int i = 0; i < 10; ++i) {
    int idx = base + i;
    if (idx < NN) {
      cursor[idx] = run;
      run += v[i];
      rowptr[idx + 1] = run;
    }
  }
  if (t == 0) rowptr[0] = 0;
}

// ---- fused node chain x->h1->h->Q->Qm (blocks 0..624) + scatter (625..) ----
#define LP 264

__global__ __launch_bounds__(256) void mlpqkv_kernel(
    const bf16* __restrict__ xbf, const bf16* __restrict__ btf,
    const float* __restrict__ bm1, const float* __restrict__ bm2,
    const float* __restrict__ bq, bf16* __restrict__ hb,
    u8* __restrict__ Hf, u8* __restrict__ Qmf,
    const int* __restrict__ ei, int* __restrict__ cursor,
    int* __restrict__ srcs) {
  __shared__ bf16 lds[16 * LP];
  if (blockIdx.x >= 625) {  // scatter part (block-uniform branch; overlaps)
    int is64 = detect64(ei);
    int e = (blockIdx.x - 625) * 256 + threadIdx.x;
    if (e < NE) {
      int s, dn;
      load_edge(ei, is64, e, s, dn);
      int slot = atomicAdd(&cursor[dn], 1);
      if (slot >= 0 && slot < NE) srcs[slot] = s;
    }
    return;
  }
  int w = threadIdx.x >> 6, lane = threadIdx.x & 63;
  int lr = lane & 15, kh = lane >> 4;
  int rb = blockIdx.x * 16;  // NN = 625*16 exactly
  f32x4 acc[4];
  // stage 1: h1 = relu(x@Wm1+bm1) -> LDS
#pragma unroll
  for (int nf = 0; nf < 4; ++nf) acc[nf] = (f32x4){0, 0, 0, 0};
  {
    const bf16* Af = xbf + (size_t)blockIdx.x * 4096;
#pragma unroll
    for (int kk = 0; kk < 8; ++kk) {
      bf16x8 af = *(const bf16x8*)(Af + kk * 512 + lane * 8);
#pragma unroll
      for (int nf = 0; nf < 4; ++nf) {
        bf16x8 bfr = *(const bf16x8*)(btf + (size_t)(((w * 4 + nf) * 8 + kk) * 512) + lane * 8);
        acc[nf] = __builtin_amdgcn_mfma_f32_16x16x32_bf16(af, bfr, acc[nf], 0, 0, 0);
      }
    }
  }
#pragma unroll
  for (int nf = 0; nf < 4; ++nf) {
    int c = w * 64 + nf * 16 + lr;
    float b1 = bm1[c];
#pragma unroll
    for (int j = 0; j < 4; ++j)
      lds[(kh * 4 + j) * LP + c] = (bf16)fmaxf(acc[nf][j] + b1, 0.0f);
  }
  __syncthreads();
  // stage 2: h = h1(LDS)@Wm2+bm2 -> LDS + hb(bf16) + Hf(fp8 8h)
  bf16x8 haf[8];
#pragma unroll
  for (int kk = 0; kk < 8; ++kk)
    haf[kk] = *(const bf16x8*)(lds + lr * LP + kh * 8 + kk * 32);
#pragma unroll
  for (int nf = 0; nf < 4; ++nf) acc[nf] = (f32x4){0, 0, 0, 0};
  {
    const bf16* Bf = btf + 65536;
#pragma unroll
    for (int kk = 0; kk < 8; ++kk) {
#pragma unroll
      for (int nf = 0; nf < 4; ++nf) {
        bf16x8 bfr = *(const bf16x8*)(Bf + (size_t)(((w * 4 + nf) * 8 + kk) * 512) + lane * 8);
        acc[nf] = __builtin_amdgcn_mfma_f32_16x16x32_bf16(haf[kk], bfr, acc[nf], 0, 0, 0);
      }
    }
  }
  __syncthreads();  // h1 reads complete before overwrite
#pragma unroll
  for (int nf = 0; nf < 4; ++nf) {
    int c = w * 64 + nf * 16 + lr;
    float b2 = bm2[c];
#pragma unroll
    for (int j = 0; j < 4; ++j) {
      int r = rb + kh * 4 + j;
      float v = acc[nf][j] + b2;
      lds[(kh * 4 + j) * LP + c] = (bf16)v;
      hb[(size_t)r * 256 + c] = (bf16)v;
      int pk = __builtin_amdgcn_cvt_pk_fp8_f32(v * 8.0f, v * 8.0f, 0, false);
      Hf[(size_t)r * 256 + c] = (u8)(pk & 0xff);
    }
  }
  __syncthreads();
  // stage 3: Q = h(LDS)@Wq+bq -> LDS
#pragma unroll
  for (int kk = 0; kk < 8; ++kk)
    haf[kk] = *(const bf16x8*)(lds + lr * LP + kh * 8 + kk * 32);
#pragma unroll
  for (int nf = 0; nf < 4; ++nf) acc[nf] = (f32x4){0, 0, 0, 0};
  {
    const bf16* Bf = btf + 2 * 65536;
#pragma unroll
    for (int kk = 0; kk < 8; ++kk) {
#pragma unroll
      for (int nf = 0; nf < 4; ++nf) {
        bf16x8 bfr = *(const bf16x8*)(Bf + (size_t)(((w * 4 + nf) * 8 + kk) * 512) + lane * 8);
        acc[nf] = __builtin_amdgcn_mfma_f32_16x16x32_bf16(haf[kk], bfr, acc[nf], 0, 0, 0);
      }
    }
  }
  __syncthreads();  // h reads complete before overwrite
#pragma unroll
  for (int nf = 0; nf < 4; ++nf) {
    int c = w * 64 + nf * 16 + lr;
    float bx = bq[c];
#pragma unroll
    for (int j = 0; j < 4; ++j)
      lds[(kh * 4 + j) * LP + c] = (bf16)(acc[nf][j] + bx);
  }
  __syncthreads();
  // stage 4: Qm = Q(LDS) @ Wk-rows (no bias; per-dst consts cancel in softmax)
#pragma unroll
  for (int kk = 0; kk < 8; ++kk)
    haf[kk] = *(const bf16x8*)(lds + lr * LP + kh * 8 + kk * 32);
#pragma unroll
  for (int nf = 0; nf < 4; ++nf) acc[nf] = (f32x4){0, 0, 0, 0};
  {
    const bf16* Bf = btf + 3 * 65536;
#pragma unroll
    for (int kk = 0; kk < 8; ++kk) {
#pragma unroll
      for (int nf = 0; nf < 4; ++nf) {
        bf16x8 bfr = *(const bf16x8*)(Bf + (size_t)(((w * 4 + nf) * 8 + kk) * 512) + lane * 8);
        acc[nf] = __builtin_amdgcn_mfma_f32_16x16x32_bf16(haf[kk], bfr, acc[nf], 0, 0, 0);
      }
    }
  }
#pragma unroll
  for (int nf = 0; nf < 4; ++nf) {
    int c = w * 64 + nf * 16 + lr;
#pragma unroll
    for (int j = 0; j < 4; ++j) {
      int r = rb + kh * 4 + j;
      float v = acc[nf][j] * 512.0f;
      int pk = __builtin_amdgcn_cvt_pk_fp8_f32(v, v, 0, false);
      Qmf[(size_t)r * 256 + c] = (u8)(pk & 0xff);
    }
  }
}

// ------- attn (r19-proven): single h-gather; fp8 MFMA alpha; scalar posMLP -------
__global__ __launch_bounds__(256) void attn_kernel(
    const u8* __restrict__ Qmf, const u8* __restrict__ Hf,
    const float* __restrict__ pos, const float* __restrict__ Wp1, const float* __restrict__ bp1,
    const int* __restrict__ rowptr, const int* __restrict__ srcs,
    bf16* __restrict__ accH, bf16* __restrict__ acc2, float* __restrict__ sattn) {
  int n = blockIdx.x * 4 + (threadIdx.x >> 6);
  int lane = threadIdx.x & 63;
  int lr = lane & 15, kh = lane >> 4;
  int d = lane * 4;
  int e0 = min(max(rowptr[n], 0), NE);
  int e1 = min(max(rowptr[n + 1], e0), NE);
  long long qfr[8];
#pragma unroll
  for (int m = 0; m < 8; ++m)
    qfr[m] = *(const long long*)(Qmf + (size_t)n * 256 + m * 32 + kh * 8);
  float px = pos[n * 3], py = pos[n * 3 + 1], pz = pos[n * 3 + 2];
  float w0[4], w1[4], w2[4], bp[4];
#pragma unroll
  for (int j = 0; j < 4; ++j) {
    w0[j] = Wp1[d + j];
    w1[j] = Wp1[256 + d + j];
    w2[j] = Wp1[512 + d + j];
    bp[j] = bp1[d + j];
  }
  float aV[4] = {0, 0, 0, 0}, aP[4] = {0, 0, 0, 0};
  float dpart = 0.0f;
  for (int base = e0; base < e1; base += 16) {
    int sv = srcs[min(base + lr, e1 - 1)];
    f32x4 al = {0.0f, 0.0f, 0.0f, 0.0f};
#pragma unroll
    for (int m = 0; m < 8; ++m) {
      long long hfr = *(const long long*)(Hf + (size_t)sv * 256 + m * 32 + kh * 8);
      al = __builtin_amdgcn_mfma_f32_16x16x32_fp8_fp8(hfr, qfr[m], al, 0, 0, 0);
    }
    float wg[4];
#pragma unroll
    for (int j = 0; j < 4; ++j) {
      int e = base + kh * 4 + j;
      // al = (512 Qm)·(8 h) = 4096 alpha; alpha/16 = al/65536
      wg[j] = (e < e1) ? __expf(al[j] * 1.52587890625e-05f) : 0.0f;
      dpart += wg[j];
    }
#pragma unroll
    for (int ii = 0; ii < 4; ++ii) {
      if (base + ii * 4 < e1) {
#pragma unroll
        for (int j = 0; j < 4; ++j) {
          float we = __int_as_float(
              __builtin_amdgcn_readlane(__float_as_int(wg[j]), ii * 16));
          int se = __builtin_amdgcn_readlane(sv, ii * 4 + j);
          unsigned vw = *(const unsigned*)(Hf + (size_t)se * 256 + lane * 4);
          float vvf[4];
          vvf[0] = __builtin_amdgcn_cvt_f32_fp8(vw, 0);
          vvf[1] = __builtin_amdgcn_cvt_f32_fp8(vw, 1);
          vvf[2] = __builtin_amdgcn_cvt_f32_fp8(vw, 2);
          vvf[3] = __builtin_amdgcn_cvt_f32_fp8(vw, 3);
          float rx = pos[se * 3] - px, ry = pos[se * 3 + 1] - py,
                rz = pos[se * 3 + 2] - pz;
#pragma unroll
          for (int jj = 0; jj < 4; ++jj) {
            float p1 = fmaf(rx, w0[jj], fmaf(ry, w1[jj], fmaf(rz, w2[jj], bp[jj])));
            p1 = fmaxf(p1, 0.0f);
            aV[jj] = fmaf(we, vvf[jj], aV[jj]);  // accumulates 8*h
            aP[jj] = fmaf(we, p1, aP[jj]);
          }
        }
      }
    }
  }
  float denom = wave_sum(dpart) * (1.0f / 16.0f);  // each edge replicated x16
  float r = 1.0f / (denom + 1e-16f);
  if (lane == 0) sattn[n] = denom * r;
  bf16x4 o1, o2;
#pragma unroll
  for (int j = 0; j < 4; ++j) {
    o1[j] = (bf16)(aV[j] * r * 0.125f);  // undo 8x h scale
    o2[j] = (bf16)(aP[j] * r);
  }
  *(bf16x4*)(accH + (size_t)n * 256 + d) = o1;
  *(bf16x4*)(acc2 + (size_t)n * 256 + d) = o2;
}

// ---- final: accH@Wv + acc2@Wp2 (fragment-major B) + residuals + 2x LN ----
__global__ __launch_bounds__(256) void final_kernel(
    const bf16* __restrict__ accH, const bf16* __restrict__ acc2,
    const bf16* __restrict__ BtWv, const bf16* __restrict__ BtWp2,
    const float* __restrict__ sattn, const float* __restrict__ bv,
    const float* __restrict__ bp2, const bf16* __restrict__ hb,
    const float* __restrict__ x, const float* __restrict__ g1,
    const float* __restrict__ b1n, const float* __restrict__ g2,
    const float* __restrict__ b2n, float* __restrict__ out) {
  __shared__ float red[2][4][16];
  int w = threadIdx.x >> 6, lane = threadIdx.x & 63;
  int lr = lane & 15, kh = lane >> 4;
  int rb = blockIdx.x * 16;  // NN = 625*16 exactly
  int arow = rb + lr;
  const bf16* ApH = accH + (size_t)arow * 256 + kh * 8;
  const bf16* ApP = acc2 + (size_t)arow * 256 + kh * 8;
  f32x4 acc[4];
#pragma unroll
  for (int nf = 0; nf < 4; ++nf) acc[nf] = (f32x4){0, 0, 0, 0};
#pragma unroll
  for (int kk = 0; kk < 8; ++kk) {
    bf16x8 afH = *(const bf16x8*)(ApH + kk * 32);
    bf16x8 afP = *(const bf16x8*)(ApP + kk * 32);
#pragma unroll
    for (int nf = 0; nf < 4; ++nf) {
      bf16x8 b1f = *(const bf16x8*)(BtWv + (size_t)(((w * 4 + nf) * 8 + kk) * 512) + lane * 8);
      acc[nf] = __builtin_amdgcn_mfma_f32_16x16x32_bf16(afH, b1f, acc[nf], 0, 0, 0);
      bf16x8 b2f = *(const bf16x8*)(BtWp2 + (size_t)(((w * 4 + nf) * 8 + kk) * 512) + lane * 8);
      acc[nf] = __builtin_amdgcn_mfma_f32_16x16x32_bf16(afP, b2f, acc[nf], 0, 0, 0);
    }
  }
  int rows[4];
  float sr[4];
#pragma unroll
  for (int j = 0; j < 4; ++j) {
    rows[j] = rb + kh * 4 + j;
    sr[j] = sattn[rows[j]];
  }
  // phase A: v = GEMMs + s*(bv+bp2) + h ; mean/var via sum & sumsq
  float s1[4] = {0, 0, 0, 0}, s2[4] = {0, 0, 0, 0};
#pragma unroll
  for (int nf = 0; nf < 4; ++nf) {
    int c = w * 64 + nf * 16 + lr;
    float bb = bv[c] + bp2[c];
#pragma unroll
    for (int j = 0; j < 4; ++j) {
      size_t idx = (size_t)rows[j] * 256 + c;
      float v = acc[nf][j] + sr[j] * bb + (float)hb[idx];
      acc[nf][j] = v;
      s1[j] += v;
      s2[j] += v * v;
    }
  }
#pragma unroll
  for (int j = 0; j < 4; ++j) {
#pragma unroll
    for (int off = 1; off < 16; off <<= 1) {
      s1[j] += __shfl_xor(s1[j], off, 64);
      s2[j] += __shfl_xor(s2[j], off, 64);
    }
  }
  if (lr == 0) {
#pragma unroll
    for (int j = 0; j < 4; ++j) {
      red[0][w][kh * 4 + j] = s1[j];
      red[1][w][kh * 4 + j] = s2[j];
    }
  }
  __syncthreads();
  float mu[4], rstd[4];
#pragma unroll
  for (int j = 0; j < 4; ++j) {
    int r = kh * 4 + j;
    float t1 = red[0][0][r] + red[0][1][r] + red[0][2][r] + red[0][3][r];
    float t2 = red[1][0][r] + red[1][1][r] + red[1][2][r] + red[1][3][r];
    mu[j] = t1 * (1.0f / 256.0f);
    rstd[j] = rsqrtf(t2 * (1.0f / 256.0f) - mu[j] * mu[j] + 1e-5f);
  }
  __syncthreads();
  // phase B: u = LN1*g1 + b1n + x ; second mean/var
#pragma unroll
  for (int j = 0; j < 4; ++j) { s1[j] = 0; s2[j] = 0; }
#pragma unroll
  for (int nf = 0; nf < 4; ++nf) {
    int c = w * 64 + nf * 16 + lr;
#pragma unroll
    for (int j = 0; j < 4; ++j) {
      float u = (acc[nf][j] - mu[j]) * rstd[j] * g1[c] + b1n[c] +
                x[(size_t)rows[j] * 256 + c];
      acc[nf][j] = u;
      s1[j] += u;
      s2[j] += u * u;
    }
  }
#pragma unroll
  for (int j = 0; j < 4; ++j) {
#pragma unroll
    for (int off = 1; off < 16; off <<= 1) {
      s1[j] += __shfl_xor(s1[j], off, 64);
      s2[j] += __shfl_xor(s2[j], off, 64);
    }
  }
  if (lr == 0) {
#pragma unroll
    for (int j = 0; j < 4; ++j) {
      red[0][w][kh * 4 + j] = s1[j];
      red[1][w][kh * 4 + j] = s2[j];
    }
  }
  __syncthreads();
#pragma unroll
  for (int j = 0; j < 4; ++j) {
    int r = kh * 4 + j;
    float t1 = red[0][0][r] + red[0][1][r] + red[0][2][r] + red[0][3][r];
    float t2 = red[1][0][r] + red[1][1][r] + red[1][2][r] + red[1][3][r];
    mu[j] = t1 * (1.0f / 256.0f);
    rstd[j] = rsqrtf(t2 * (1.0f / 256.0f) - mu[j] * mu[j] + 1e-5f);
  }
  // phase C: out = LN2*g2 + b2n
#pragma unroll
  for (int j = 0; j < 4; ++j) {
#pragma unroll
    for (int nf = 0; nf < 4; ++nf) {
      int c = w * 64 + nf * 16 + lr;
      out[(size_t)rows[j] * 256 + c] =
          (acc[nf][j] - mu[j]) * rstd[j] * g2[c] + b2n[c];
    }
  }
}

extern "C" void kernel_launch(void* const* d_in, const int* in_sizes, int n_in,
                              void* d_out, int out_size, void* d_ws, size_t ws_size,
                              hipStream_t stream) {
  (void)in_sizes; (void)n_in; (void)out_size; (void)ws_size;
  const float* x   = (const float*)d_in[0];
  const int*   ei  = (const int*)d_in[1];
  const float* pos = (const float*)d_in[2];
  const float* Wm1 = (const float*)d_in[3];
  const float* bm1 = (const float*)d_in[4];
  const float* Wm2 = (const float*)d_in[5];
  const float* bm2 = (const float*)d_in[6];
  const float* Wq  = (const float*)d_in[7];
  const float* bq  = (const float*)d_in[8];
  const float* Wk  = (const float*)d_in[9];
  const float* bk  = (const float*)d_in[10];
  const float* Wv  = (const float*)d_in[11];
  const float* bv  = (const float*)d_in[12];
  const float* Wp1 = (const float*)d_in[13];
  const float* bp1 = (const float*)d_in[14];
  const float* Wp2 = (const float*)d_in[15];
  const float* bp2 = (const float*)d_in[16];
  const float* g1  = (const float*)d_in[17];
  const float* b1n = (const float*)d_in[18];
  const float* g2  = (const float*)d_in[19];
  const float* b2n = (const float*)d_in[20];
  (void)bk;  // per-dst const Q·bk cancels in segment softmax

  const size_t ND = (size_t)NN * 256;
  char* p = (char*)d_ws;
  auto alloc = [&](size_t bytes) {
    char* r = p;
    p += (bytes + 255) & ~(size_t)255;
    return r;
  };
  bf16* btbase = (bf16*)alloc(6 * 65536 * sizeof(bf16));
  bf16* xbf   = (bf16*)alloc(ND * 2);
  bf16* hb    = (bf16*)alloc(ND * 2);
  u8*   Hf    = (u8*)alloc(ND);
  u8*   Qmf   = (u8*)alloc(ND);
  bf16* accH  = (bf16*)alloc(ND * 2);
  bf16* acc2  = (bf16*)alloc(ND * 2);
  float* sattn = (float*)alloc(NN * 4);
  int* deg    = (int*)alloc(NN * 4);
  int* rowptr = (int*)alloc((NN + 1) * 4);
  int* cursor = (int*)alloc(NN * 4);
  int* srcs   = (int*)alloc(NE * 4);

  hipMemsetAsync(deg, 0, NN * 4, stream);

  PrepArgs pa;
  pa.w[0] = Wm1; pa.w[1] = Wm2; pa.w[2] = Wq; pa.w[3] = Wk; pa.w[4] = Wv; pa.w[5] = Wp2;
  for (int i = 0; i < 6; ++i) pa.o[i] = btbase + i * 65536;
  pa.x = x; pa.xbf = xbf; pa.ei = ei; pa.deg = deg;
  prep_kernel<<<192 + 1250 + (NE + 255) / 256, 256, 0, stream>>>(pa);

  scan_kernel<<<1, 1024, 0, stream>>>(deg, rowptr, cursor);

  mlpqkv_kernel<<<625 + (NE + 255) / 256, 256, 0, stream>>>(
      xbf, btbase, bm1, bm2, bq, hb, Hf, Qmf, ei, cursor, srcs);

  attn_kernel<<<NN / 4, 256, 0, stream>>>(Qmf, Hf, pos, Wp1, bp1, rowptr, srcs,
                                          accH, acc2, sattn);

  final_kernel<<<NN / 16, 256, 0, stream>>>(accH, acc2, btbase + 4 * 65536,
                                            btbase + 5 * 65536, sattn, bv, bp2,
                                            hb, x, g1, b1n, g2, b2n,
                                            (float*)d_out);
}

// Round 24
// 134.105 us; speedup vs baseline: 1.5467x; 1.0113x over previous
//
#include <hip/hip_runtime.h>
#include <hip/hip_bf16.h>
#include <math.h>

// AGTBlock. r22 (135.6us) + attn V-phase LDS row-staging, TYPE-CONSISTENT u32
// accesses (r20/r23 NaN root cause: long long writes + unsigned reads = strict
// aliasing UB -> compiler reordered LDS reads past writes).
//  alpha = Q·K = (Q@Wk^T)·h_src + const(dst) -> Qm = Q@Wk-rows; gather only h.
//  Sum attn·V = (Sum attn·h)@Wv + (Sum attn)·bv -> Wv GEMM fused into final.
//  Fragment-major weights/x (1KB coalesced MFMA fragment loads).
// launches: memset, prep(frags+hist), scan, mlpqkv+scatter, attn, final.

#define NN 10000
#define NE 320000

typedef __bf16 bf16;
typedef __bf16 bf16x8 __attribute__((ext_vector_type(8)));
typedef __bf16 bf16x4 __attribute__((ext_vector_type(4)));
typedef float f32x4 __attribute__((ext_vector_type(4)));
typedef unsigned char u8;
typedef unsigned int u32;

__device__ __forceinline__ float wave_sum(float v) {
#pragma unroll
  for (int off = 32; off; off >>= 1) v += __shfl_xor(v, off, 64);
  return v;
}

__device__ __forceinline__ int detect64(const int* __restrict__ ei) {
  return (ei[1] | ei[3] | ei[5] | ei[7]) == 0;
}

__device__ __forceinline__ void load_edge(const int* __restrict__ ei, int is64,
                                          int e, int& s, int& dn) {
  if (is64) {
    const long long* e64 = (const long long*)ei;
    s = (int)e64[e];
    dn = (int)e64[NE + e];
  } else {
    s = ei[e];
    dn = ei[NE + e];
  }
  s = min(max(s, 0), NN - 1);
  dn = min(max(dn, 0), NN - 1);
}

// ------- prep: weights+x -> fragment-major bf16, + edge histogram -------
// mats 0,1,2,4,5 transposed (B[n][k]=W[k][n]); mat 3 = Wk NON-transposed.
struct PrepArgs { const float* w[6]; bf16* o[6]; const float* x; bf16* xbf;
                  const int* ei; int* deg; };

__global__ __launch_bounds__(256) void prep_kernel(PrepArgs pa) {
  int b = blockIdx.x;
  int w = threadIdx.x >> 6, lane = threadIdx.x & 63;
  int lr = lane & 15, kh = lane >> 4;
  if (b < 192) {  // 6 mats x 128 frags, 1 frag/wave
    int f = b * 4 + w;
    int mat = f >> 7, fr = f & 127;
    int nfp = fr >> 3, kk = fr & 7;
    const float* ws = pa.w[mat];
    bf16x8 o;
    if (mat == 3) {  // Wk rows: contiguous reads
      const float* s = ws + (size_t)(nfp * 16 + lr) * 256 + kk * 32 + kh * 8;
      float4 a0 = *(const float4*)s;
      float4 a1 = *(const float4*)(s + 4);
      o[0] = (bf16)a0.x; o[1] = (bf16)a0.y; o[2] = (bf16)a0.z; o[3] = (bf16)a0.w;
      o[4] = (bf16)a1.x; o[5] = (bf16)a1.y; o[6] = (bf16)a1.z; o[7] = (bf16)a1.w;
    } else {
#pragma unroll
      for (int e = 0; e < 8; ++e)
        o[e] = (bf16)ws[(kk * 32 + kh * 8 + e) * 256 + nfp * 16 + lr];
    }
    *(bf16x8*)(pa.o[mat] + (size_t)fr * 512 + lane * 8) = o;
  } else if (b < 192 + 1250) {  // x -> fragment-major bf16 (5000 frags)
    int g = (b - 192) * 4 + w;
    int rt = g >> 3, kk = g & 7;
    const float* xs = pa.x + (size_t)(rt * 16 + lr) * 256 + kk * 32 + kh * 8;
    float4 a0 = *(const float4*)xs;
    float4 a1 = *(const float4*)(xs + 4);
    bf16x8 o;
    o[0] = (bf16)a0.x; o[1] = (bf16)a0.y; o[2] = (bf16)a0.z; o[3] = (bf16)a0.w;
    o[4] = (bf16)a1.x; o[5] = (bf16)a1.y; o[6] = (bf16)a1.z; o[7] = (bf16)a1.w;
    *(bf16x8*)(pa.xbf + (size_t)g * 512 + lane * 8) = o;
  } else {  // histogram of dst (deg pre-zeroed via memset)
    int is64 = detect64(pa.ei);
    int e = (b - 1442) * 256 + threadIdx.x;
    if (e < NE) {
      int s, dn;
      load_edge(pa.ei, is64, e, s, dn);
      atomicAdd(&pa.deg[dn], 1);
    }
  }
}

__global__ __launch_bounds__(1024) void scan_kernel(
    const int* __restrict__ deg, int* __restrict__ rowptr,
    int* __restrict__ cursor) {
  __shared__ int wsum[16];
  int t = threadIdx.x, wid = t >> 6, lane = t & 63;
  int base = t * 10;
  int v[10];
  int s = 0;
#pragma unroll
  for (int i = 0; i < 10; ++i) {
    int idx = base + i;
    v[i] = (idx < NN) ? deg[idx] : 0;
    s += v[i];
  }
  int x = s;
#pragma unroll
  for (int off = 1; off < 64; off <<= 1) {
    int y = __shfl_up(x, off, 64);
    if (lane >= off) x += y;
  }
  if (lane == 63) wsum[wid] = x;
  __syncthreads();
  if (wid == 0) {
    int ws = (lane < 16) ? wsum[lane] : 0;
#pragma unroll
    for (int off = 1; off < 16; off <<= 1) {
      int y = __shfl_up(ws, off, 64);
      if (lane >= off) ws += y;
    }
    if (lane < 16) wsum[lane] = ws;
  }
  __syncthreads();
  int run = ((wid > 0) ? wsum[wid - 1] : 0) + x - s;  // exclusive prefix
#pragma unroll
  for (int i = 0; i < 10; ++i) {
    int idx = base + i;
    if (idx < NN) {
      cursor[idx] = run;
      run += v[i];
      rowptr[idx + 1] = run;
    }
  }
  if (t == 0) rowptr[0] = 0;
}

// ---- fused node chain x->h1->h->Q->Qm (blocks 0..624) + scatter (625..) ----
#define LP 264

__global__ __launch_bounds__(256) void mlpqkv_kernel(
    const bf16* __restrict__ xbf, const bf16* __restrict__ btf,
    const float* __restrict__ bm1, const float* __restrict__ bm2,
    const float* __restrict__ bq, bf16* __restrict__ hb,
    u8* __restrict__ Hf, u8* __restrict__ Qmf,
    const int* __restrict__ ei, int* __restrict__ cursor,
    int* __restrict__ srcs) {
  __shared__ bf16 lds[16 * LP];
  if (blockIdx.x >= 625) {  // scatter part (block-uniform branch; overlaps)
    int is64 = detect64(ei);
    int e = (blockIdx.x - 625) * 256 + threadIdx.x;
    if (e < NE) {
      int s, dn;
      load_edge(ei, is64, e, s, dn);
      int slot = atomicAdd(&cursor[dn], 1);
      if (slot >= 0 && slot < NE) srcs[slot] = s;
    }
    return;
  }
  int w = threadIdx.x >> 6, lane = threadIdx.x & 63;
  int lr = lane & 15, kh = lane >> 4;
  int rb = blockIdx.x * 16;  // NN = 625*16 exactly
  f32x4 acc[4];
  // stage 1: h1 = relu(x@Wm1+bm1) -> LDS
#pragma unroll
  for (int nf = 0; nf < 4; ++nf) acc[nf] = (f32x4){0, 0, 0, 0};
  {
    const bf16* Af = xbf + (size_t)blockIdx.x * 4096;
#pragma unroll
    for (int kk = 0; kk < 8; ++kk) {
      bf16x8 af = *(const bf16x8*)(Af + kk * 512 + lane * 8);
#pragma unroll
      for (int nf = 0; nf < 4; ++nf) {
        bf16x8 bfr = *(const bf16x8*)(btf + (size_t)(((w * 4 + nf) * 8 + kk) * 512) + lane * 8);
        acc[nf] = __builtin_amdgcn_mfma_f32_16x16x32_bf16(af, bfr, acc[nf], 0, 0, 0);
      }
    }
  }
#pragma unroll
  for (int nf = 0; nf < 4; ++nf) {
    int c = w * 64 + nf * 16 + lr;
    float b1 = bm1[c];
#pragma unroll
    for (int j = 0; j < 4; ++j)
      lds[(kh * 4 + j) * LP + c] = (bf16)fmaxf(acc[nf][j] + b1, 0.0f);
  }
  __syncthreads();
  // stage 2: h = h1(LDS)@Wm2+bm2 -> LDS + hb(bf16) + Hf(fp8 8h)
  bf16x8 haf[8];
#pragma unroll
  for (int kk = 0; kk < 8; ++kk)
    haf[kk] = *(const bf16x8*)(lds + lr * LP + kh * 8 + kk * 32);
#pragma unroll
  for (int nf = 0; nf < 4; ++nf) acc[nf] = (f32x4){0, 0, 0, 0};
  {
    const bf16* Bf = btf + 65536;
#pragma unroll
    for (int kk = 0; kk < 8; ++kk) {
#pragma unroll
      for (int nf = 0; nf < 4; ++nf) {
        bf16x8 bfr = *(const bf16x8*)(Bf + (size_t)(((w * 4 + nf) * 8 + kk) * 512) + lane * 8);
        acc[nf] = __builtin_amdgcn_mfma_f32_16x16x32_bf16(haf[kk], bfr, acc[nf], 0, 0, 0);
      }
    }
  }
  __syncthreads();  // h1 reads complete before overwrite
#pragma unroll
  for (int nf = 0; nf < 4; ++nf) {
    int c = w * 64 + nf * 16 + lr;
    float b2 = bm2[c];
#pragma unroll
    for (int j = 0; j < 4; ++j) {
      int r = rb + kh * 4 + j;
      float v = acc[nf][j] + b2;
      lds[(kh * 4 + j) * LP + c] = (bf16)v;
      hb[(size_t)r * 256 + c] = (bf16)v;
      int pk = __builtin_amdgcn_cvt_pk_fp8_f32(v * 8.0f, v * 8.0f, 0, false);
      Hf[(size_t)r * 256 + c] = (u8)(pk & 0xff);
    }
  }
  __syncthreads();
  // stage 3: Q = h(LDS)@Wq+bq -> LDS
#pragma unroll
  for (int kk = 0; kk < 8; ++kk)
    haf[kk] = *(const bf16x8*)(lds + lr * LP + kh * 8 + kk * 32);
#pragma unroll
  for (int nf = 0; nf < 4; ++nf) acc[nf] = (f32x4){0, 0, 0, 0};
  {
    const bf16* Bf = btf + 2 * 65536;
#pragma unroll
    for (int kk = 0; kk < 8; ++kk) {
#pragma unroll
      for (int nf = 0; nf < 4; ++nf) {
        bf16x8 bfr = *(const bf16x8*)(Bf + (size_t)(((w * 4 + nf) * 8 + kk) * 512) + lane * 8);
        acc[nf] = __builtin_amdgcn_mfma_f32_16x16x32_bf16(haf[kk], bfr, acc[nf], 0, 0, 0);
      }
    }
  }
  __syncthreads();  // h reads complete before overwrite
#pragma unroll
  for (int nf = 0; nf < 4; ++nf) {
    int c = w * 64 + nf * 16 + lr;
    float bx = bq[c];
#pragma unroll
    for (int j = 0; j < 4; ++j)
      lds[(kh * 4 + j) * LP + c] = (bf16)(acc[nf][j] + bx);
  }
  __syncthreads();
  // stage 4: Qm = Q(LDS) @ Wk-rows (no bias; per-dst consts cancel in softmax)
#pragma unroll
  for (int kk = 0; kk < 8; ++kk)
    haf[kk] = *(const bf16x8*)(lds + lr * LP + kh * 8 + kk * 32);
#pragma unroll
  for (int nf = 0; nf < 4; ++nf) acc[nf] = (f32x4){0, 0, 0, 0};
  {
    const bf16* Bf = btf + 3 * 65536;
#pragma unroll
    for (int kk = 0; kk < 8; ++kk) {
#pragma unroll
      for (int nf = 0; nf < 4; ++nf) {
        bf16x8 bfr = *(const bf16x8*)(Bf + (size_t)(((w * 4 + nf) * 8 + kk) * 512) + lane * 8);
        acc[nf] = __builtin_amdgcn_mfma_f32_16x16x32_bf16(haf[kk], bfr, acc[nf], 0, 0, 0);
      }
    }
  }
#pragma unroll
  for (int nf = 0; nf < 4; ++nf) {
    int c = w * 64 + nf * 16 + lr;
#pragma unroll
    for (int j = 0; j < 4; ++j) {
      int r = rb + kh * 4 + j;
      float v = acc[nf][j] * 512.0f;
      int pk = __builtin_amdgcn_cvt_pk_fp8_f32(v, v, 0, false);
      Qmf[(size_t)r * 256 + c] = (u8)(pk & 0xff);
    }
  }
}

// ------- attn: single h-gather; rows staged to per-wave LDS (u32-typed) -------
#define HPW 66  // staging pitch in words (264B): write 2-4-way, read 2-way banks

__global__ __launch_bounds__(256) void attn_kernel(
    const u8* __restrict__ Qmf, const u8* __restrict__ Hf,
    const float* __restrict__ pos, const float* __restrict__ Wp1, const float* __restrict__ bp1,
    const int* __restrict__ rowptr, const int* __restrict__ srcs,
    bf16* __restrict__ accH, bf16* __restrict__ acc2, float* __restrict__ sattn) {
  __shared__ u32 hstage[4][16 * HPW];
  int wv = threadIdx.x >> 6;
  int n = blockIdx.x * 4 + wv;
  int lane = threadIdx.x & 63;
  int lr = lane & 15, kh = lane >> 4;
  int d = lane * 4;
  int e0 = min(max(rowptr[n], 0), NE);
  int e1 = min(max(rowptr[n + 1], e0), NE);
  long long qfr[8];
#pragma unroll
  for (int m = 0; m < 8; ++m)
    qfr[m] = *(const long long*)(Qmf + (size_t)n * 256 + m * 32 + kh * 8);
  float px = pos[n * 3], py = pos[n * 3 + 1], pz = pos[n * 3 + 2];
  float w0[4], w1[4], w2[4], bp[4];
#pragma unroll
  for (int j = 0; j < 4; ++j) {
    w0[j] = Wp1[d + j];
    w1[j] = Wp1[256 + d + j];
    w2[j] = Wp1[512 + d + j];
    bp[j] = bp1[d + j];
  }
  u32* hs = hstage[wv];
  float aV[4] = {0, 0, 0, 0}, aP[4] = {0, 0, 0, 0};
  float dpart = 0.0f;
  for (int base = e0; base < e1; base += 16) {
    int sv = srcs[min(base + lr, e1 - 1)];
    long long hfr[8];
#pragma unroll
    for (int m = 0; m < 8; ++m)
      hfr[m] = *(const long long*)(Hf + (size_t)sv * 256 + m * 32 + kh * 8);
    // stage this wave's 16 gathered rows to LDS (u32 stores; same type as read)
#pragma unroll
    for (int m = 0; m < 8; ++m) {
      int wi = lr * HPW + m * 8 + kh * 2;
      hs[wi] = (u32)(unsigned long long)hfr[m];
      hs[wi + 1] = (u32)(((unsigned long long)hfr[m]) >> 32);
    }
    __builtin_amdgcn_sched_barrier(0);  // keep LDS reads below the writes
    f32x4 al = {0.0f, 0.0f, 0.0f, 0.0f};
#pragma unroll
    for (int m = 0; m < 8; ++m)
      al = __builtin_amdgcn_mfma_f32_16x16x32_fp8_fp8(hfr[m], qfr[m], al, 0, 0, 0);
    float wg[4];
#pragma unroll
    for (int j = 0; j < 4; ++j) {
      int e = base + kh * 4 + j;
      // al = (512 Qm)·(8 h) = 4096 alpha; alpha/16 = al/65536
      wg[j] = (e < e1) ? __expf(al[j] * 1.52587890625e-05f) : 0.0f;
      dpart += wg[j];
    }
#pragma unroll
    for (int ii = 0; ii < 4; ++ii) {
      if (base + ii * 4 < e1) {
#pragma unroll
        for (int j = 0; j < 4; ++j) {
          int i = ii * 4 + j;
          float we = __int_as_float(
              __builtin_amdgcn_readlane(__float_as_int(wg[j]), ii * 16));
          int se = __builtin_amdgcn_readlane(sv, i);
          u32 vw = hs[i * HPW + lane];
          float vvf[4];
          vvf[0] = __builtin_amdgcn_cvt_f32_fp8(vw, 0);
          vvf[1] = __builtin_amdgcn_cvt_f32_fp8(vw, 1);
          vvf[2] = __builtin_amdgcn_cvt_f32_fp8(vw, 2);
          vvf[3] = __builtin_amdgcn_cvt_f32_fp8(vw, 3);
          float rx = pos[se * 3] - px, ry = pos[se * 3 + 1] - py,
                rz = pos[se * 3 + 2] - pz;
#pragma unroll
          for (int jj = 0; jj < 4; ++jj) {
            float p1 = fmaf(rx, w0[jj], fmaf(ry, w1[jj], fmaf(rz, w2[jj], bp[jj])));
            p1 = fmaxf(p1, 0.0f);
            aV[jj] = fmaf(we, vvf[jj], aV[jj]);  // accumulates 8*h
            aP[jj] = fmaf(we, p1, aP[jj]);
          }
        }
      }
    }
    __builtin_amdgcn_sched_barrier(0);  // next chunk's writes stay below reads
  }
  float denom = wave_sum(dpart) * (1.0f / 16.0f);  // each edge replicated x16
  float r = 1.0f / (denom + 1e-16f);
  if (lane == 0) sattn[n] = denom * r;
  bf16x4 o1, o2;
#pragma unroll
  for (int j = 0; j < 4; ++j) {
    o1[j] = (bf16)(aV[j] * r * 0.125f);  // undo 8x h scale
    o2[j] = (bf16)(aP[j] * r);
  }
  *(bf16x4*)(accH + (size_t)n * 256 + d) = o1;
  *(bf16x4*)(acc2 + (size_t)n * 256 + d) = o2;
}

// ---- final: accH@Wv + acc2@Wp2 (fragment-major B) + residuals + 2x LN ----
__global__ __launch_bounds__(256) void final_kernel(
    const bf16* __restrict__ accH, const bf16* __restrict__ acc2,
    const bf16* __restrict__ BtWv, const bf16* __restrict__ BtWp2,
    const float* __restrict__ sattn, const float* __restrict__ bv,
    const float* __restrict__ bp2, const bf16* __restrict__ hb,
    const float* __restrict__ x, const float* __restrict__ g1,
    const float* __restrict__ b1n, const float* __restrict__ g2,
    const float* __restrict__ b2n, float* __restrict__ out) {
  __shared__ float red[2][4][16];
  int w = threadIdx.x >> 6, lane = threadIdx.x & 63;
  int lr = lane & 15, kh = lane >> 4;
  int rb = blockIdx.x * 16;  // NN = 625*16 exactly
  int arow = rb + lr;
  const bf16* ApH = accH + (size_t)arow * 256 + kh * 8;
  const bf16* ApP = acc2 + (size_t)arow * 256 + kh * 8;
  f32x4 acc[4];
#pragma unroll
  for (int nf = 0; nf < 4; ++nf) acc[nf] = (f32x4){0, 0, 0, 0};
#pragma unroll
  for (int kk = 0; kk < 8; ++kk) {
    bf16x8 afH = *(const bf16x8*)(ApH + kk * 32);
    bf16x8 afP = *(const bf16x8*)(ApP + kk * 32);
#pragma unroll
    for (int nf = 0; nf < 4; ++nf) {
      bf16x8 b1f = *(const bf16x8*)(BtWv + (size_t)(((w * 4 + nf) * 8 + kk) * 512) + lane * 8);
      acc[nf] = __builtin_amdgcn_mfma_f32_16x16x32_bf16(afH, b1f, acc[nf], 0, 0, 0);
      bf16x8 b2f = *(const bf16x8*)(BtWp2 + (size_t)(((w * 4 + nf) * 8 + kk) * 512) + lane * 8);
      acc[nf] = __builtin_amdgcn_mfma_f32_16x16x32_bf16(afP, b2f, acc[nf], 0, 0, 0);
    }
  }
  int rows[4];
  float sr[4];
#pragma unroll
  for (int j = 0; j < 4; ++j) {
    rows[j] = rb + kh * 4 + j;
    sr[j] = sattn[rows[j]];
  }
  // phase A: v = GEMMs + s*(bv+bp2) + h ; mean/var via sum & sumsq
  float s1[4] = {0, 0, 0, 0}, s2[4] = {0, 0, 0, 0};
#pragma unroll
  for (int nf = 0; nf < 4; ++nf) {
    int c = w * 64 + nf * 16 + lr;
    float bb = bv[c] + bp2[c];
#pragma unroll
    for (int j = 0; j < 4; ++j) {
      size_t idx = (size_t)rows[j] * 256 + c;
      float v = acc[nf][j] + sr[j] * bb + (float)hb[idx];
      acc[nf][j] = v;
      s1[j] += v;
      s2[j] += v * v;
    }
  }
#pragma unroll
  for (int j = 0; j < 4; ++j) {
#pragma unroll
    for (int off = 1; off < 16; off <<= 1) {
      s1[j] += __shfl_xor(s1[j], off, 64);
      s2[j] += __shfl_xor(s2[j], off, 64);
    }
  }
  if (lr == 0) {
#pragma unroll
    for (int j = 0; j < 4; ++j) {
      red[0][w][kh * 4 + j] = s1[j];
      red[1][w][kh * 4 + j] = s2[j];
    }
  }
  __syncthreads();
  float mu[4], rstd[4];
#pragma unroll
  for (int j = 0; j < 4; ++j) {
    int r = kh * 4 + j;
    float t1 = red[0][0][r] + red[0][1][r] + red[0][2][r] + red[0][3][r];
    float t2 = red[1][0][r] + red[1][1][r] + red[1][2][r] + red[1][3][r];
    mu[j] = t1 * (1.0f / 256.0f);
    rstd[j] = rsqrtf(t2 * (1.0f / 256.0f) - mu[j] * mu[j] + 1e-5f);
  }
  __syncthreads();
  // phase B: u = LN1*g1 + b1n + x ; second mean/var
#pragma unroll
  for (int j = 0; j < 4; ++j) { s1[j] = 0; s2[j] = 0; }
#pragma unroll
  for (int nf = 0; nf < 4; ++nf) {
    int c = w * 64 + nf * 16 + lr;
#pragma unroll
    for (int j = 0; j < 4; ++j) {
      float u = (acc[nf][j] - mu[j]) * rstd[j] * g1[c] + b1n[c] +
                x[(size_t)rows[j] * 256 + c];
      acc[nf][j] = u;
      s1[j] += u;
      s2[j] += u * u;
    }
  }
#pragma unroll
  for (int j = 0; j < 4; ++j) {
#pragma unroll
    for (int off = 1; off < 16; off <<= 1) {
      s1[j] += __shfl_xor(s1[j], off, 64);
      s2[j] += __shfl_xor(s2[j], off, 64);
    }
  }
  if (lr == 0) {
#pragma unroll
    for (int j = 0; j < 4; ++j) {
      red[0][w][kh * 4 + j] = s1[j];
      red[1][w][kh * 4 + j] = s2[j];
    }
  }
  __syncthreads();
#pragma unroll
  for (int j = 0; j < 4; ++j) {
    int r = kh * 4 + j;
    float t1 = red[0][0][r] + red[0][1][r] + red[0][2][r] + red[0][3][r];
    float t2 = red[1][0][r] + red[1][1][r] + red[1][2][r] + red[1][3][r];
    mu[j] = t1 * (1.0f / 256.0f);
    rstd[j] = rsqrtf(t2 * (1.0f / 256.0f) - mu[j] * mu[j] + 1e-5f);
  }
  // phase C: out = LN2*g2 + b2n
#pragma unroll
  for (int j = 0; j < 4; ++j) {
#pragma unroll
    for (int nf = 0; nf < 4; ++nf) {
      int c = w * 64 + nf * 16 + lr;
      out[(size_t)rows[j] * 256 + c] =
          (acc[nf][j] - mu[j]) * rstd[j] * g2[c] + b2n[c];
    }
  }
}

extern "C" void kernel_launch(void* const* d_in, const int* in_sizes, int n_in,
                              void* d_out, int out_size, void* d_ws, size_t ws_size,
                              hipStream_t stream) {
  (void)in_sizes; (void)n_in; (void)out_size; (void)ws_size;
  const float* x   = (const float*)d_in[0];
  const int*   ei  = (const int*)d_in[1];
  const float* pos = (const float*)d_in[2];
  const float* Wm1 = (const float*)d_in[3];
  const float* bm1 = (const float*)d_in[4];
  const float* Wm2 = (const float*)d_in[5];
  const float* bm2 = (const float*)d_in[6];
  const float* Wq  = (const float*)d_in[7];
  const float* bq  = (const float*)d_in[8];
  const float* Wk  = (const float*)d_in[9];
  const float* bk  = (const float*)d_in[10];
  const float* Wv  = (const float*)d_in[11];
  const float* bv  = (const float*)d_in[12];
  const float* Wp1 = (const float*)d_in[13];
  const float* bp1 = (const float*)d_in[14];
  const float* Wp2 = (const float*)d_in[15];
  const float* bp2 = (const float*)d_in[16];
  const float* g1  = (const float*)d_in[17];
  const float* b1n = (const float*)d_in[18];
  const float* g2  = (const float*)d_in[19];
  const float* b2n = (const float*)d_in[20];
  (void)bk;  // per-dst const Q·bk cancels in segment softmax

  const size_t ND = (size_t)NN * 256;
  char* p = (char*)d_ws;
  auto alloc = [&](size_t bytes) {
    char* r = p;
    p += (bytes + 255) & ~(size_t)255;
    return r;
  };
  bf16* btbase = (bf16*)alloc(6 * 65536 * sizeof(bf16));
  bf16* xbf   = (bf16*)alloc(ND * 2);
  bf16* hb    = (bf16*)alloc(ND * 2);
  u8*   Hf    = (u8*)alloc(ND);
  u8*   Qmf   = (u8*)alloc(ND);
  bf16* accH  = (bf16*)alloc(ND * 2);
  bf16* acc2  = (bf16*)alloc(ND * 2);
  float* sattn = (float*)alloc(NN * 4);
  int* deg    = (int*)alloc(NN * 4);
  int* rowptr = (int*)alloc((NN + 1) * 4);
  int* cursor = (int*)alloc(NN * 4);
  int* srcs   = (int*)alloc(NE * 4);

  hipMemsetAsync(deg, 0, NN * 4, stream);

  PrepArgs pa;
  pa.w[0] = Wm1; pa.w[1] = Wm2; pa.w[2] = Wq; pa.w[3] = Wk; pa.w[4] = Wv; pa.w[5] = Wp2;
  for (int i = 0; i < 6; ++i) pa.o[i] = btbase + i * 65536;
  pa.x = x; pa.xbf = xbf; pa.ei = ei; pa.deg = deg;
  prep_kernel<<<192 + 1250 + (NE + 255) / 256, 256, 0, stream>>>(pa);

  scan_kernel<<<1, 1024, 0, stream>>>(deg, rowptr, cursor);

  mlpqkv_kernel<<<625 + (NE + 255) / 256, 256, 0, stream>>>(
      xbf, btbase, bm1, bm2, bq, hb, Hf, Qmf, ei, cursor, srcs);

  attn_kernel<<<NN / 4, 256, 0, stream>>>(Qmf, Hf, pos, Wp1, bp1, rowptr, srcs,
                                          accH, acc2, sattn);

  final_kernel<<<NN / 16, 256, 0, stream>>>(accH, acc2, btbase + 4 * 65536,
                                            btbase + 5 * 65536, sattn, bv, bp2,
                                            hb, x, g1, b1n, g2, b2n,
                                            (float*)d_out);
}

// Round 25
// 130.551 us; speedup vs baseline: 1.5888x; 1.0272x over previous
//
#include <hip/hip_runtime.h>
#include <hip/hip_bf16.h>
#include <math.h>

// AGTBlock. r24 (134.1us) + attn: srcs prefetch across sched_barrier + pos4
// (padded float4) parallel gather with readlane sharing (removes 48 serial
// uniform pos loads per 16-edge chunk).
//  alpha = Q·K = (Q@Wk^T)·h_src + const(dst) -> Qm = Q@Wk-rows; gather only h.
//  Sum attn·V = (Sum attn·h)@Wv + (Sum attn)·bv -> Wv GEMM fused into final.
//  Fragment-major weights/x; attn V-phase reads LDS-staged rows (u32-typed).
// launches: memset, prep(frags+hist+pos4), scan, mlpqkv+scatter, attn, final.

#define NN 10000
#define NE 320000

typedef __bf16 bf16;
typedef __bf16 bf16x8 __attribute__((ext_vector_type(8)));
typedef __bf16 bf16x4 __attribute__((ext_vector_type(4)));
typedef float f32x4 __attribute__((ext_vector_type(4)));
typedef unsigned char u8;
typedef unsigned int u32;

__device__ __forceinline__ float wave_sum(float v) {
#pragma unroll
  for (int off = 32; off; off >>= 1) v += __shfl_xor(v, off, 64);
  return v;
}

__device__ __forceinline__ float rdlane(float v, int l) {
  return __int_as_float(__builtin_amdgcn_readlane(__float_as_int(v), l));
}

__device__ __forceinline__ int detect64(const int* __restrict__ ei) {
  return (ei[1] | ei[3] | ei[5] | ei[7]) == 0;
}

__device__ __forceinline__ void load_edge(const int* __restrict__ ei, int is64,
                                          int e, int& s, int& dn) {
  if (is64) {
    const long long* e64 = (const long long*)ei;
    s = (int)e64[e];
    dn = (int)e64[NE + e];
  } else {
    s = ei[e];
    dn = ei[NE + e];
  }
  s = min(max(s, 0), NN - 1);
  dn = min(max(dn, 0), NN - 1);
}

// --- prep: weights+x -> fragment-major bf16, + edge histogram + pos4 ---
// mats 0,1,2,4,5 transposed (B[n][k]=W[k][n]); mat 3 = Wk NON-transposed.
struct PrepArgs { const float* w[6]; bf16* o[6]; const float* x; bf16* xbf;
                  const int* ei; int* deg; const float* pos; float4* pos4; };

__global__ __launch_bounds__(256) void prep_kernel(PrepArgs pa) {
  int b = blockIdx.x;
  int w = threadIdx.x >> 6, lane = threadIdx.x & 63;
  int lr = lane & 15, kh = lane >> 4;
  if (b < 192) {  // 6 mats x 128 frags, 1 frag/wave
    int f = b * 4 + w;
    int mat = f >> 7, fr = f & 127;
    int nfp = fr >> 3, kk = fr & 7;
    const float* ws = pa.w[mat];
    bf16x8 o;
    if (mat == 3) {  // Wk rows: contiguous reads
      const float* s = ws + (size_t)(nfp * 16 + lr) * 256 + kk * 32 + kh * 8;
      float4 a0 = *(const float4*)s;
      float4 a1 = *(const float4*)(s + 4);
      o[0] = (bf16)a0.x; o[1] = (bf16)a0.y; o[2] = (bf16)a0.z; o[3] = (bf16)a0.w;
      o[4] = (bf16)a1.x; o[5] = (bf16)a1.y; o[6] = (bf16)a1.z; o[7] = (bf16)a1.w;
    } else {
#pragma unroll
      for (int e = 0; e < 8; ++e)
        o[e] = (bf16)ws[(kk * 32 + kh * 8 + e) * 256 + nfp * 16 + lr];
    }
    *(bf16x8*)(pa.o[mat] + (size_t)fr * 512 + lane * 8) = o;
  } else if (b < 192 + 1250) {  // x -> fragment-major bf16 (5000 frags)
    int g = (b - 192) * 4 + w;
    int rt = g >> 3, kk = g & 7;
    const float* xs = pa.x + (size_t)(rt * 16 + lr) * 256 + kk * 32 + kh * 8;
    float4 a0 = *(const float4*)xs;
    float4 a1 = *(const float4*)(xs + 4);
    bf16x8 o;
    o[0] = (bf16)a0.x; o[1] = (bf16)a0.y; o[2] = (bf16)a0.z; o[3] = (bf16)a0.w;
    o[4] = (bf16)a1.x; o[5] = (bf16)a1.y; o[6] = (bf16)a1.z; o[7] = (bf16)a1.w;
    *(bf16x8*)(pa.xbf + (size_t)g * 512 + lane * 8) = o;
  } else if (b < 192 + 1250 + 1250) {  // histogram of dst (deg pre-zeroed)
    int is64 = detect64(pa.ei);
    int e = (b - 1442) * 256 + threadIdx.x;
    if (e < NE) {
      int s, dn;
      load_edge(pa.ei, is64, e, s, dn);
      atomicAdd(&pa.deg[dn], 1);
    }
  } else {  // pos -> padded float4
    int nn = (b - 2692) * 256 + threadIdx.x;
    if (nn < NN) {
      float4 o;
      o.x = pa.pos[nn * 3];
      o.y = pa.pos[nn * 3 + 1];
      o.z = pa.pos[nn * 3 + 2];
      o.w = 0.0f;
      pa.pos4[nn] = o;
    }
  }
}

__global__ __launch_bounds__(1024) void scan_kernel(
    const int* __restrict__ deg, int* __restrict__ rowptr,
    int* __restrict__ cursor) {
  __shared__ int wsum[16];
  int t = threadIdx.x, wid = t >> 6, lane = t & 63;
  int base = t * 10;
  int v[10];
  int s = 0;
#pragma unroll
  for (int i = 0; i < 10; ++i) {
    int idx = base + i;
    v[i] = (idx < NN) ? deg[idx] : 0;
    s += v[i];
  }
  int x = s;
#pragma unroll
  for (int off = 1; off < 64; off <<= 1) {
    int y = __shfl_up(x, off, 64);
    if (lane >= off) x += y;
  }
  if (lane == 63) wsum[wid] = x;
  __syncthreads();
  if (wid == 0) {
    int ws = (lane < 16) ? wsum[lane] : 0;
#pragma unroll
    for (int off = 1; off < 16; off <<= 1) {
      int y = __shfl_up(ws, off, 64);
      if (lane >= off) ws += y;
    }
    if (lane < 16) wsum[lane] = ws;
  }
  __syncthreads();
  int run = ((wid > 0) ? wsum[wid - 1] : 0) + x - s;  // exclusive prefix
#pragma unroll
  for (int i = 0; i < 10; ++i) {
    int idx = base + i;
    if (idx < NN) {
      cursor[idx] = run;
      run += v[i];
      rowptr[idx + 1] = run;
    }
  }
  if (t == 0) rowptr[0] = 0;
}

// ---- fused node chain x->h1->h->Q->Qm (blocks 0..624) + scatter (625..) ----
#define LP 264

__global__ __launch_bounds__(256) void mlpqkv_kernel(
    const bf16* __restrict__ xbf, const bf16* __restrict__ btf,
    const float* __restrict__ bm1, const float* __restrict__ bm2,
    const float* __restrict__ bq, bf16* __restrict__ hb,
    u8* __restrict__ Hf, u8* __restrict__ Qmf,
    const int* __restrict__ ei, int* __restrict__ cursor,
    int* __restrict__ srcs) {
  __shared__ bf16 lds[16 * LP];
  if (blockIdx.x >= 625) {  // scatter part (block-uniform branch; overlaps)
    int is64 = detect64(ei);
    int e = (blockIdx.x - 625) * 256 + threadIdx.x;
    if (e < NE) {
      int s, dn;
      load_edge(ei, is64, e, s, dn);
      int slot = atomicAdd(&cursor[dn], 1);
      if (slot >= 0 && slot < NE) srcs[slot] = s;
    }
    return;
  }
  int w = threadIdx.x >> 6, lane = threadIdx.x & 63;
  int lr = lane & 15, kh = lane >> 4;
  int rb = blockIdx.x * 16;  // NN = 625*16 exactly
  f32x4 acc[4];
  // stage 1: h1 = relu(x@Wm1+bm1) -> LDS
#pragma unroll
  for (int nf = 0; nf < 4; ++nf) acc[nf] = (f32x4){0, 0, 0, 0};
  {
    const bf16* Af = xbf + (size_t)blockIdx.x * 4096;
#pragma unroll
    for (int kk = 0; kk < 8; ++kk) {
      bf16x8 af = *(const bf16x8*)(Af + kk * 512 + lane * 8);
#pragma unroll
      for (int nf = 0; nf < 4; ++nf) {
        bf16x8 bfr = *(const bf16x8*)(btf + (size_t)(((w * 4 + nf) * 8 + kk) * 512) + lane * 8);
        acc[nf] = __builtin_amdgcn_mfma_f32_16x16x32_bf16(af, bfr, acc[nf], 0, 0, 0);
      }
    }
  }
#pragma unroll
  for (int nf = 0; nf < 4; ++nf) {
    int c = w * 64 + nf * 16 + lr;
    float b1 = bm1[c];
#pragma unroll
    for (int j = 0; j < 4; ++j)
      lds[(kh * 4 + j) * LP + c] = (bf16)fmaxf(acc[nf][j] + b1, 0.0f);
  }
  __syncthreads();
  // stage 2: h = h1(LDS)@Wm2+bm2 -> LDS + hb(bf16) + Hf(fp8 8h)
  bf16x8 haf[8];
#pragma unroll
  for (int kk = 0; kk < 8; ++kk)
    haf[kk] = *(const bf16x8*)(lds + lr * LP + kh * 8 + kk * 32);
#pragma unroll
  for (int nf = 0; nf < 4; ++nf) acc[nf] = (f32x4){0, 0, 0, 0};
  {
    const bf16* Bf = btf + 65536;
#pragma unroll
    for (int kk = 0; kk < 8; ++kk) {
#pragma unroll
      for (int nf = 0; nf < 4; ++nf) {
        bf16x8 bfr = *(const bf16x8*)(Bf + (size_t)(((w * 4 + nf) * 8 + kk) * 512) + lane * 8);
        acc[nf] = __builtin_amdgcn_mfma_f32_16x16x32_bf16(haf[kk], bfr, acc[nf], 0, 0, 0);
      }
    }
  }
  __syncthreads();  // h1 reads complete before overwrite
#pragma unroll
  for (int nf = 0; nf < 4; ++nf) {
    int c = w * 64 + nf * 16 + lr;
    float b2 = bm2[c];
#pragma unroll
    for (int j = 0; j < 4; ++j) {
      int r = rb + kh * 4 + j;
      float v = acc[nf][j] + b2;
      lds[(kh * 4 + j) * LP + c] = (bf16)v;
      hb[(size_t)r * 256 + c] = (bf16)v;
      int pk = __builtin_amdgcn_cvt_pk_fp8_f32(v * 8.0f, v * 8.0f, 0, false);
      Hf[(size_t)r * 256 + c] = (u8)(pk & 0xff);
    }
  }
  __syncthreads();
  // stage 3: Q = h(LDS)@Wq+bq -> LDS
#pragma unroll
  for (int kk = 0; kk < 8; ++kk)
    haf[kk] = *(const bf16x8*)(lds + lr * LP + kh * 8 + kk * 32);
#pragma unroll
  for (int nf = 0; nf < 4; ++nf) acc[nf] = (f32x4){0, 0, 0, 0};
  {
    const bf16* Bf = btf + 2 * 65536;
#pragma unroll
    for (int kk = 0; kk < 8; ++kk) {
#pragma unroll
      for (int nf = 0; nf < 4; ++nf) {
        bf16x8 bfr = *(const bf16x8*)(Bf + (size_t)(((w * 4 + nf) * 8 + kk) * 512) + lane * 8);
        acc[nf] = __builtin_amdgcn_mfma_f32_16x16x32_bf16(haf[kk], bfr, acc[nf], 0, 0, 0);
      }
    }
  }
  __syncthreads();  // h reads complete before overwrite
#pragma unroll
  for (int nf = 0; nf < 4; ++nf) {
    int c = w * 64 + nf * 16 + lr;
    float bx = bq[c];
#pragma unroll
    for (int j = 0; j < 4; ++j)
      lds[(kh * 4 + j) * LP + c] = (bf16)(acc[nf][j] + bx);
  }
  __syncthreads();
  // stage 4: Qm = Q(LDS) @ Wk-rows (no bias; per-dst consts cancel in softmax)
#pragma unroll
  for (int kk = 0; kk < 8; ++kk)
    haf[kk] = *(const bf16x8*)(lds + lr * LP + kh * 8 + kk * 32);
#pragma unroll
  for (int nf = 0; nf < 4; ++nf) acc[nf] = (f32x4){0, 0, 0, 0};
  {
    const bf16* Bf = btf + 3 * 65536;
#pragma unroll
    for (int kk = 0; kk < 8; ++kk) {
#pragma unroll
      for (int nf = 0; nf < 4; ++nf) {
        bf16x8 bfr = *(const bf16x8*)(Bf + (size_t)(((w * 4 + nf) * 8 + kk) * 512) + lane * 8);
        acc[nf] = __builtin_amdgcn_mfma_f32_16x16x32_bf16(haf[kk], bfr, acc[nf], 0, 0, 0);
      }
    }
  }
#pragma unroll
  for (int nf = 0; nf < 4; ++nf) {
    int c = w * 64 + nf * 16 + lr;
#pragma unroll
    for (int j = 0; j < 4; ++j) {
      int r = rb + kh * 4 + j;
      float v = acc[nf][j] * 512.0f;
      int pk = __builtin_amdgcn_cvt_pk_fp8_f32(v, v, 0, false);
      Qmf[(size_t)r * 256 + c] = (u8)(pk & 0xff);
    }
  }
}

// --- attn: single h-gather; LDS-staged rows (u32); pos4 parallel gather ---
#define HPW 66  // staging pitch in words (264B)

__global__ __launch_bounds__(256) void attn_kernel(
    const u8* __restrict__ Qmf, const u8* __restrict__ Hf,
    const float4* __restrict__ pos4, const float* __restrict__ Wp1,
    const float* __restrict__ bp1,
    const int* __restrict__ rowptr, const int* __restrict__ srcs,
    bf16* __restrict__ accH, bf16* __restrict__ acc2, float* __restrict__ sattn) {
  __shared__ u32 hstage[4][16 * HPW];
  int wv = threadIdx.x >> 6;
  int n = blockIdx.x * 4 + wv;
  int lane = threadIdx.x & 63;
  int lr = lane & 15, kh = lane >> 4;
  int d = lane * 4;
  int e0 = min(max(rowptr[n], 0), NE);
  int e1 = min(max(rowptr[n + 1], e0), NE);
  long long qfr[8];
#pragma unroll
  for (int m = 0; m < 8; ++m)
    qfr[m] = *(const long long*)(Qmf + (size_t)n * 256 + m * 32 + kh * 8);
  float4 pn = pos4[n];
  float w0[4], w1[4], w2[4], bp[4];
#pragma unroll
  for (int j = 0; j < 4; ++j) {
    w0[j] = Wp1[d + j];
    w1[j] = Wp1[256 + d + j];
    w2[j] = Wp1[512 + d + j];
    bp[j] = bp1[d + j];
  }
  u32* hs = hstage[wv];
  float aV[4] = {0, 0, 0, 0}, aP[4] = {0, 0, 0, 0};
  float dpart = 0.0f;
  int sv = (e0 < e1) ? srcs[min(e0 + lr, e1 - 1)] : 0;
  for (int base = e0; base < e1; base += 16) {
    int nb = base + 16;
    int svn = (nb < e1) ? srcs[min(nb + lr, e1 - 1)] : 0;  // prefetch next
    // per-lane pos diff of this lane's edge (shared via readlane in V phase)
    float4 ps = pos4[sv];
    float pdx = ps.x - pn.x, pdy = ps.y - pn.y, pdz = ps.z - pn.z;
    long long hfr[8];
#pragma unroll
    for (int m = 0; m < 8; ++m)
      hfr[m] = *(const long long*)(Hf + (size_t)sv * 256 + m * 32 + kh * 8);
    // stage this wave's 16 gathered rows to LDS (u32 stores; same type as read)
#pragma unroll
    for (int m = 0; m < 8; ++m) {
      int wi = lr * HPW + m * 8 + kh * 2;
      hs[wi] = (u32)(unsigned long long)hfr[m];
      hs[wi + 1] = (u32)(((unsigned long long)hfr[m]) >> 32);
    }
    __builtin_amdgcn_sched_barrier(0);  // keep LDS reads below the writes
    f32x4 al = {0.0f, 0.0f, 0.0f, 0.0f};
#pragma unroll
    for (int m = 0; m < 8; ++m)
      al = __builtin_amdgcn_mfma_f32_16x16x32_fp8_fp8(hfr[m], qfr[m], al, 0, 0, 0);
    float wg[4];
#pragma unroll
    for (int j = 0; j < 4; ++j) {
      int e = base + kh * 4 + j;
      // al = (512 Qm)·(8 h) = 4096 alpha; alpha/16 = al/65536
      wg[j] = (e < e1) ? __expf(al[j] * 1.52587890625e-05f) : 0.0f;
      dpart += wg[j];
    }
#pragma unroll
    for (int ii = 0; ii < 4; ++ii) {
      if (base + ii * 4 < e1) {
#pragma unroll
        for (int j = 0; j < 4; ++j) {
          int i = ii * 4 + j;
          float we = rdlane(wg[j], ii * 16);
          float rx = rdlane(pdx, i), ry = rdlane(pdy, i), rz = rdlane(pdz, i);
          u32 vw = hs[i * HPW + lane];
          float vvf[4];
          vvf[0] = __builtin_amdgcn_cvt_f32_fp8(vw, 0);
          vvf[1] = __builtin_amdgcn_cvt_f32_fp8(vw, 1);
          vvf[2] = __builtin_amdgcn_cvt_f32_fp8(vw, 2);
          vvf[3] = __builtin_amdgcn_cvt_f32_fp8(vw, 3);
#pragma unroll
          for (int jj = 0; jj < 4; ++jj) {
            float p1 = fmaf(rx, w0[jj], fmaf(ry, w1[jj], fmaf(rz, w2[jj], bp[jj])));
            p1 = fmaxf(p1, 0.0f);
            aV[jj] = fmaf(we, vvf[jj], aV[jj]);  // accumulates 8*h
            aP[jj] = fmaf(we, p1, aP[jj]);
          }
        }
      }
    }
    __builtin_amdgcn_sched_barrier(0);  // next chunk's writes stay below reads
    sv = svn;
  }
  float denom = wave_sum(dpart) * (1.0f / 16.0f);  // each edge replicated x16
  float r = 1.0f / (denom + 1e-16f);
  if (lane == 0) sattn[n] = denom * r;
  bf16x4 o1, o2;
#pragma unroll
  for (int j = 0; j < 4; ++j) {
    o1[j] = (bf16)(aV[j] * r * 0.125f);  // undo 8x h scale
    o2[j] = (bf16)(aP[j] * r);
  }
  *(bf16x4*)(accH + (size_t)n * 256 + d) = o1;
  *(bf16x4*)(acc2 + (size_t)n * 256 + d) = o2;
}

// ---- final: accH@Wv + acc2@Wp2 (fragment-major B) + residuals + 2x LN ----
__global__ __launch_bounds__(256) void final_kernel(
    const bf16* __restrict__ accH, const bf16* __restrict__ acc2,
    const bf16* __restrict__ BtWv, const bf16* __restrict__ BtWp2,
    const float* __restrict__ sattn, const float* __restrict__ bv,
    const float* __restrict__ bp2, const bf16* __restrict__ hb,
    const float* __restrict__ x, const float* __restrict__ g1,
    const float* __restrict__ b1n, const float* __restrict__ g2,
    const float* __restrict__ b2n, float* __restrict__ out) {
  __shared__ float red[2][4][16];
  int w = threadIdx.x >> 6, lane = threadIdx.x & 63;
  int lr = lane & 15, kh = lane >> 4;
  int rb = blockIdx.x * 16;  // NN = 625*16 exactly
  int arow = rb + lr;
  const bf16* ApH = accH + (size_t)arow * 256 + kh * 8;
  const bf16* ApP = acc2 + (size_t)arow * 256 + kh * 8;
  f32x4 acc[4];
#pragma unroll
  for (int nf = 0; nf < 4; ++nf) acc[nf] = (f32x4){0, 0, 0, 0};
#pragma unroll
  for (int kk = 0; kk < 8; ++kk) {
    bf16x8 afH = *(const bf16x8*)(ApH + kk * 32);
    bf16x8 afP = *(const bf16x8*)(ApP + kk * 32);
#pragma unroll
    for (int nf = 0; nf < 4; ++nf) {
      bf16x8 b1f = *(const bf16x8*)(BtWv + (size_t)(((w * 4 + nf) * 8 + kk) * 512) + lane * 8);
      acc[nf] = __builtin_amdgcn_mfma_f32_16x16x32_bf16(afH, b1f, acc[nf], 0, 0, 0);
      bf16x8 b2f = *(const bf16x8*)(BtWp2 + (size_t)(((w * 4 + nf) * 8 + kk) * 512) + lane * 8);
      acc[nf] = __builtin_amdgcn_mfma_f32_16x16x32_bf16(afP, b2f, acc[nf], 0, 0, 0);
    }
  }
  int rows[4];
  float sr[4];
#pragma unroll
  for (int j = 0; j < 4; ++j) {
    rows[j] = rb + kh * 4 + j;
    sr[j] = sattn[rows[j]];
  }
  // phase A: v = GEMMs + s*(bv+bp2) + h ; mean/var via sum & sumsq
  float s1[4] = {0, 0, 0, 0}, s2[4] = {0, 0, 0, 0};
#pragma unroll
  for (int nf = 0; nf < 4; ++nf) {
    int c = w * 64 + nf * 16 + lr;
    float bb = bv[c] + bp2[c];
#pragma unroll
    for (int j = 0; j < 4; ++j) {
      size_t idx = (size_t)rows[j] * 256 + c;
      float v = acc[nf][j] + sr[j] * bb + (float)hb[idx];
      acc[nf][j] = v;
      s1[j] += v;
      s2[j] += v * v;
    }
  }
#pragma unroll
  for (int j = 0; j < 4; ++j) {
#pragma unroll
    for (int off = 1; off < 16; off <<= 1) {
      s1[j] += __shfl_xor(s1[j], off, 64);
      s2[j] += __shfl_xor(s2[j], off, 64);
    }
  }
  if (lr == 0) {
#pragma unroll
    for (int j = 0; j < 4; ++j) {
      red[0][w][kh * 4 + j] = s1[j];
      red[1][w][kh * 4 + j] = s2[j];
    }
  }
  __syncthreads();
  float mu[4], rstd[4];
#pragma unroll
  for (int j = 0; j < 4; ++j) {
    int r = kh * 4 + j;
    float t1 = red[0][0][r] + red[0][1][r] + red[0][2][r] + red[0][3][r];
    float t2 = red[1][0][r] + red[1][1][r] + red[1][2][r] + red[1][3][r];
    mu[j] = t1 * (1.0f / 256.0f);
    rstd[j] = rsqrtf(t2 * (1.0f / 256.0f) - mu[j] * mu[j] + 1e-5f);
  }
  __syncthreads();
  // phase B: u = LN1*g1 + b1n + x ; second mean/var
#pragma unroll
  for (int j = 0; j < 4; ++j) { s1[j] = 0; s2[j] = 0; }
#pragma unroll
  for (int nf = 0; nf < 4; ++nf) {
    int c = w * 64 + nf * 16 + lr;
#pragma unroll
    for (int j = 0; j < 4; ++j) {
      float u = (acc[nf][j] - mu[j]) * rstd[j] * g1[c] + b1n[c] +
                x[(size_t)rows[j] * 256 + c];
      acc[nf][j] = u;
      s1[j] += u;
      s2[j] += u * u;
    }
  }
#pragma unroll
  for (int j = 0; j < 4; ++j) {
#pragma unroll
    for (int off = 1; off < 16; off <<= 1) {
      s1[j] += __shfl_xor(s1[j], off, 64);
      s2[j] += __shfl_xor(s2[j], off, 64);
    }
  }
  if (lr == 0) {
#pragma unroll
    for (int j = 0; j < 4; ++j) {
      red[0][w][kh * 4 + j] = s1[j];
      red[1][w][kh * 4 + j] = s2[j];
    }
  }
  __syncthreads();
#pragma unroll
  for (int j = 0; j < 4; ++j) {
    int r = kh * 4 + j;
    float t1 = red[0][0][r] + red[0][1][r] + red[0][2][r] + red[0][3][r];
    float t2 = red[1][0][r] + red[1][1][r] + red[1][2][r] + red[1][3][r];
    mu[j] = t1 * (1.0f / 256.0f);
    rstd[j] = rsqrtf(t2 * (1.0f / 256.0f) - mu[j] * mu[j] + 1e-5f);
  }
  // phase C: out = LN2*g2 + b2n
#pragma unroll
  for (int j = 0; j < 4; ++j) {
#pragma unroll
    for (int nf = 0; nf < 4; ++nf) {
      int c = w * 64 + nf * 16 + lr;
      out[(size_t)rows[j] * 256 + c] =
          (acc[nf][j] - mu[j]) * rstd[j] * g2[c] + b2n[c];
    }
  }
}

extern "C" void kernel_launch(void* const* d_in, const int* in_sizes, int n_in,
                              void* d_out, int out_size, void* d_ws, size_t ws_size,
                              hipStream_t stream) {
  (void)in_sizes; (void)n_in; (void)out_size; (void)ws_size;
  const float* x   = (const float*)d_in[0];
  const int*   ei  = (const int*)d_in[1];
  const float* pos = (const float*)d_in[2];
  const float* Wm1 = (const float*)d_in[3];
  const float* bm1 = (const float*)d_in[4];
  const float* Wm2 = (const float*)d_in[5];
  const float* bm2 = (const float*)d_in[6];
  const float* Wq  = (const float*)d_in[7];
  const float* bq  = (const float*)d_in[8];
  const float* Wk  = (const float*)d_in[9];
  const float* bk  = (const float*)d_in[10];
  const float* Wv  = (const float*)d_in[11];
  const float* bv  = (const float*)d_in[12];
  const float* Wp1 = (const float*)d_in[13];
  const float* bp1 = (const float*)d_in[14];
  const float* Wp2 = (const float*)d_in[15];
  const float* bp2 = (const float*)d_in[16];
  const float* g1  = (const float*)d_in[17];
  const float* b1n = (const float*)d_in[18];
  const float* g2  = (const float*)d_in[19];
  const float* b2n = (const float*)d_in[20];
  (void)bk;  // per-dst const Q·bk cancels in segment softmax

  const size_t ND = (size_t)NN * 256;
  char* p = (char*)d_ws;
  auto alloc = [&](size_t bytes) {
    char* r = p;
    p += (bytes + 255) & ~(size_t)255;
    return r;
  };
  bf16* btbase = (bf16*)alloc(6 * 65536 * sizeof(bf16));
  bf16* xbf   = (bf16*)alloc(ND * 2);
  bf16* hb    = (bf16*)alloc(ND * 2);
  u8*   Hf    = (u8*)alloc(ND);
  u8*   Qmf   = (u8*)alloc(ND);
  bf16* accH  = (bf16*)alloc(ND * 2);
  bf16* acc2  = (bf16*)alloc(ND * 2);
  float* sattn = (float*)alloc(NN * 4);
  float4* pos4 = (float4*)alloc(NN * 16);
  int* deg    = (int*)alloc(NN * 4);
  int* rowptr = (int*)alloc((NN + 1) * 4);
  int* cursor = (int*)alloc(NN * 4);
  int* srcs   = (int*)alloc(NE * 4);

  hipMemsetAsync(deg, 0, NN * 4, stream);

  PrepArgs pa;
  pa.w[0] = Wm1; pa.w[1] = Wm2; pa.w[2] = Wq; pa.w[3] = Wk; pa.w[4] = Wv; pa.w[5] = Wp2;
  for (int i = 0; i < 6; ++i) pa.o[i] = btbase + i * 65536;
  pa.x = x; pa.xbf = xbf; pa.ei = ei; pa.deg = deg;
  pa.pos = pos; pa.pos4 = pos4;
  prep_kernel<<<192 + 1250 + 1250 + 40, 256, 0, stream>>>(pa);

  scan_kernel<<<1, 1024, 0, stream>>>(deg, rowptr, cursor);

  mlpqkv_kernel<<<625 + (NE + 255) / 256, 256, 0, stream>>>(
      xbf, btbase, bm1, bm2, bq, hb, Hf, Qmf, ei, cursor, srcs);

  attn_kernel<<<NN / 4, 256, 0, stream>>>(Qmf, Hf, pos4, Wp1, bp1, rowptr, srcs,
                                          accH, acc2, sattn);

  final_kernel<<<NN / 16, 256, 0, stream>>>(accH, acc2, btbase + 4 * 65536,
                                            btbase + 5 * 65536, sattn, bv, bp2,
                                            hb, x, g1, b1n, g2, b2n,
                                            (float*)d_out);
}